// Round 7
// baseline (334.830 us; speedup 1.0000x reference)
//
#include <hip/hip_runtime.h>
#include <math.h>

typedef unsigned short u16;
typedef unsigned int u32;
typedef __attribute__((ext_vector_type(8))) short short8;
typedef __attribute__((ext_vector_type(4))) float f32x4;
typedef __attribute__((ext_vector_type(4))) unsigned short ushort4v;

#define B_ 8
#define S_ 2048
#define D_ 2048
#define H_ 16
#define RLEN 4194304   // S_*D_ elems per batch sample
#define NCHUNK 512

static __device__ __forceinline__ u16 f2bf(float f) {
    union { float f; u32 u; } v; v.f = f;
    u32 r = v.u + 0x7fffu + ((v.u >> 16) & 1u);
    return (u16)(r >> 16);
}
static __device__ __forceinline__ float bf2f(u16 u) {
    union { u32 u; float f; } v; v.u = ((u32)u) << 16;
    return v.f;
}
// fast tanh-GELU (|err vs exact| <= ~3e-3, well within bf16 budget); gate folded by caller
static __device__ __forceinline__ float gelu_fast(float v) {
    float z = 1.5957691216057308f * v * (1.0f + 0.044715f * v * v);  // 2*sqrt(2/pi)*...
    float e = __expf(z);
    float r = __builtin_amdgcn_rcpf(e + 1.0f);   // e=inf -> r=0 -> v ; e=0 -> r=1 -> 0
    return v * (1.0f - r);
}

typedef const __attribute__((address_space(1))) u32* gas1_t;
typedef __attribute__((address_space(3))) u32* las3_t;
static __device__ __forceinline__ void gload_lds16(const void* g, void* l) {
    __builtin_amdgcn_global_load_lds((gas1_t)g, (las3_t)l, 16, 0, 0);
}

// ---------------- Kernel 1: router partial dots (+ fused x->bf16 swizzled) --
template<int XB>
__global__ __launch_bounds__(256) void router_partial(const float* __restrict__ x,
                                                      const float* __restrict__ sw,
                                                      float* __restrict__ part,
                                                      u16* __restrict__ xb) {
    int c = blockIdx.x;
    int t = threadIdx.x;
    const int chunk = RLEN / NCHUNK;        // 8192
    int base = c * chunk;
    float acc[8][8];
#pragma unroll
    for (int b = 0; b < 8; b++)
#pragma unroll
        for (int e = 0; e < 8; e++) acc[b][e] = 0.f;

    for (int it = 0; it < chunk / (256 * 4); ++it) {   // 8 iterations
        int i = base + (it * 256 + t) * 4;
        float4 xv[8], sv[8];
#pragma unroll
        for (int b = 0; b < 8; b++) xv[b] = *(const float4*)&x[(size_t)b * RLEN + i];
#pragma unroll
        for (int e = 0; e < 8; e++) sv[e] = *(const float4*)&sw[(size_t)e * RLEN + i];
        if (XB) {
            int row = i >> 7, col = i & 127;
            int scol = (((col >> 3) ^ (row & 7)) << 3) | (col & 7);
#pragma unroll
            for (int b = 0; b < 8; b++) {
                ushort4v u;
                u.x = f2bf(xv[b].x); u.y = f2bf(xv[b].y);
                u.z = f2bf(xv[b].z); u.w = f2bf(xv[b].w);
                *(ushort4v*)&xb[(size_t)b * RLEN + (size_t)row * 128 + scol] = u;
            }
        }
#pragma unroll
        for (int b = 0; b < 8; b++)
#pragma unroll
            for (int e = 0; e < 8; e++)
                acc[b][e] += xv[b].x * sv[e].x + xv[b].y * sv[e].y +
                             xv[b].z * sv[e].z + xv[b].w * sv[e].w;
    }

    __shared__ float red[4][64];
    int lane = t & 63, wv = t >> 6;
#pragma unroll
    for (int q = 0; q < 64; q++) {
        float v = acc[q >> 3][q & 7];
#pragma unroll
        for (int m = 32; m >= 1; m >>= 1) v += __shfl_xor(v, m, 64);
        if (lane == 0) red[wv][q] = v;
    }
    __syncthreads();
    if (t < 64) {
        float s = red[0][t] + red[1][t] + red[2][t] + red[3][t];
        part[(size_t)t * NCHUNK + c] = s;
    }
}

// ---------------- Kernel 2: reduce + softmax + top-2 + combined b2 bias ----
__global__ __launch_bounds__(128) void router_finish(const float* __restrict__ part,
                                                     const float* __restrict__ swb,
                                                     const float* __restrict__ b2,
                                                     float* __restrict__ gate,
                                                     int* __restrict__ idx,
                                                     float* __restrict__ bc) {
    int t = threadIdx.x;
    __shared__ float lg[64];
    __shared__ float sg[16];
    __shared__ int   si[16];
    if (t < 64) {
        float s = 0.f;
        for (int c = 0; c < NCHUNK; c++) s += part[(size_t)t * NCHUNK + c];
        lg[t] = s + swb[t & 7];
    }
    __syncthreads();
    if (t < 8) {
        int b = t;
        float m = -1e30f;
        for (int e = 0; e < 8; e++) m = fmaxf(m, lg[b * 8 + e]);
        float p[8]; float sum = 0.f;
        for (int e = 0; e < 8; e++) { p[e] = expf(lg[b * 8 + e] - m); sum += p[e]; }
        for (int e = 0; e < 8; e++) p[e] /= sum;
        int i1 = 0; float v1 = p[0];
        for (int e = 1; e < 8; e++) if (p[e] > v1) { v1 = p[e]; i1 = e; }
        int i2 = -1; float v2 = -1.f;
        for (int e = 0; e < 8; e++) if (e != i1 && p[e] > v2) { v2 = p[e]; i2 = e; }
        gate[b * 2 + 0] = v1; gate[b * 2 + 1] = v2;
        idx[b * 2 + 0] = i1;  idx[b * 2 + 1] = i2;
        sg[b * 2] = v1; sg[b * 2 + 1] = v2;
        si[b * 2] = i1; si[b * 2 + 1] = i2;
    }
    __syncthreads();
    for (int b = 0; b < 8; b++)
        bc[b * 128 + t] = sg[b * 2] * b2[si[b * 2] * 128 + t] +
                          sg[b * 2 + 1] * b2[si[b * 2 + 1] * 128 + t];
}

// ---------------- Kernel 3a: w1/w2 -> bf16 (w1 swizzled) -------------------
__global__ __launch_bounds__(256) void convert_w12(const float* __restrict__ w1,
                                                   const float* __restrict__ w2,
                                                   u16* __restrict__ w1b,
                                                   u16* __restrict__ w2b) {
    int i4 = (blockIdx.x * 256 + threadIdx.x) * 4;
    if (i4 < 131072) {
        int k = i4 & 127, f = (i4 >> 7) & 127;
        float4 v = *(const float4*)&w1[i4];
        int sc = ((((k >> 3) ^ (f & 7)) << 3) | (k & 7));
        ushort4v u;
        u.x = f2bf(v.x); u.y = f2bf(v.y); u.z = f2bf(v.z); u.w = f2bf(v.w);
        *(ushort4v*)&w1b[(i4 & ~127) + sc] = u;
    } else {
        int j = i4 - 131072;
        float4 v = *(const float4*)&w2[j];
        ushort4v u;
        u.x = f2bf(v.x); u.y = f2bf(v.y); u.z = f2bf(v.z); u.w = f2bf(v.w);
        *(ushort4v*)&w2b[j] = u;
    }
}

// ---------------- Kernel 3b: w3 -> bf16 ------------------------------------
__global__ __launch_bounds__(256) void convert_w3(const float* __restrict__ w3,
                                                  u16* __restrict__ w3b) {
    size_t i = ((size_t)blockIdx.x * 256 + threadIdx.x) * 4;
    float4 v = *(const float4*)&w3[i];
    u16* d = &w3b[i];
    d[0] = f2bf(v.x); d[1] = f2bf(v.y); d[2] = f2bf(v.z); d[3] = f2bf(v.w);
}

// ---------------- Kernel 4: expert MLP v3 — pipelined 32-row subtiles ------
// Per iteration: GEMM1(st+1) || GEMM2(st) || GELU(st+1); one barrier/iter.
// hb double-buffered so the GELU VALU of subtile st+1 hides under GEMM2(st).
template<int XB>
__global__ __launch_bounds__(512) void mlp_kernel(const void* __restrict__ xsrc_,
                                                  const u16* __restrict__ w1b,
                                                  const u16* __restrict__ w2b,
                                                  const float* __restrict__ b1,
                                                  const float* __restrict__ gate,
                                                  const int* __restrict__ idx,
                                                  const float* __restrict__ bc,
                                                  u16* __restrict__ y) {
    __shared__ __align__(16) u16 w1s[256 * 128];   // 64 KB (both experts)
    __shared__ __align__(16) u16 xs[2][64 * 128];  // 32 KB (dbuf of 64-row tiles)
    __shared__ __align__(16) u16 hb[2][32 * 256];  // 32 KB (dbuf of 32-row subtiles)
    const int t = threadIdx.x, lane = t & 63, w = t >> 6;
    const int wr = w >> 2, wq = w & 3;             // wr 0-1 (row half), wq 0-3
    const int l15 = lane & 15, l4 = lane >> 4;
    const int b = blockIdx.y, grp = blockIdx.x;
    const size_t xbase = (size_t)b * RLEN;
    const size_t gbase = xbase + (size_t)grp * 65536;
    const int e0 = idx[b * 2], e1 = idx[b * 2 + 1];
    const int slot = wq >> 1;
    const float gw = gate[b * 2 + slot];
    const float* b1p = b1 + (slot ? e1 : e0) * 128;

    float b1v[4];
#pragma unroll
    for (int nt = 0; nt < 4; nt++) b1v[nt] = b1p[(wq & 1) * 64 + nt * 16 + l15];
    float bcv[2];
#pragma unroll
    for (int n = 0; n < 2; n++) bcv[n] = bc[b * 128 + wq * 32 + n * 16 + l15];

    // W2' fragments in registers: wave owns d-block wq*32..+32, K = 256 f
    short8 w2f[2][8];
#pragma unroll
    for (int n = 0; n < 2; n++) {
        int d = wq * 32 + n * 16 + l15;
#pragma unroll
        for (int kb = 0; kb < 8; kb++) {
            int e = (kb >= 4) ? e1 : e0;
            int f = (kb & 3) * 32 + l4 * 8;
            w2f[n][kb] = *(const short8*)&w2b[((size_t)(e * 128 + d)) * 128 + f];
        }
    }

    // stage W1 for both experts (pre-swizzled global -> linear LDS)
#pragma unroll
    for (int p = 0; p < 8; p++) {
        int elem = p * 4096 + t * 8;
        int frow = elem >> 7, col = elem & 127;
        int e = (frow >= 128) ? e1 : e0;
        gload_lds16(w1b + ((size_t)(e * 128 + (frow & 127))) * 128 + col,
                    (char*)w1s + elem * 2);
    }
    // stage x tiles 0 and 1
    if (XB) {
        const u16* xbp = (const u16*)xsrc_;
#pragma unroll
        for (int T = 0; T < 2; T++)
            gload_lds16(xbp + gbase + T * 8192 + t * 8, (char*)&xs[T][0] + t * 16);
        // each tile = 8192 elems = 512thr*16B... need 2 loads per tile:
#pragma unroll
        for (int T = 0; T < 2; T++)
            gload_lds16(xbp + gbase + T * 8192 + 4096 + t * 8,
                        (char*)&xs[T][0] + 8192 + t * 16);
        asm volatile("s_waitcnt vmcnt(0)" ::: "memory");
    } else {
        const float* xf = (const float*)xsrc_;
#pragma unroll
        for (int T = 0; T < 2; T++)
#pragma unroll
            for (int p = 0; p < 4; p++) {
                int elem = p * 2048 + t * 4;
                int row = elem >> 7, col = elem & 127;
                float4 v = *(const float4*)&xf[gbase + T * 8192 + elem];
                ushort4v u;
                u.x = f2bf(v.x); u.y = f2bf(v.y); u.z = f2bf(v.z); u.w = f2bf(v.w);
                *(ushort4v*)((char*)&xs[T][0] + row * 256 +
                             (((col >> 3) ^ (row & 7)) << 4) + (col & 7) * 2) = u;
            }
        asm volatile("s_waitcnt vmcnt(0) lgkmcnt(0)" ::: "memory");
    }
    __builtin_amdgcn_s_barrier();

    // ---- helpers as lambdas ----
    auto G1 = [&](int st, f32x4* a1) {
        const u16* xc = &xs[(st >> 1) & 1][0];
        int rbase = (st & 1) * 32 + wr * 16 + l15;
#pragma unroll
        for (int nt = 0; nt < 4; nt++) a1[nt] = (f32x4){0.f, 0.f, 0.f, 0.f};
#pragma unroll
        for (int kb = 0; kb < 4; kb++) {
            int kg = kb * 4 + l4;
            short8 a = *(const short8*)&xc[rbase * 128 + ((kg ^ (rbase & 7)) << 3)];
#pragma unroll
            for (int nt = 0; nt < 4; nt++) {
                int fr = wq * 64 + nt * 16 + l15;
                short8 bb = *(const short8*)&w1s[fr * 128 + ((kg ^ (fr & 7)) << 3)];
                a1[nt] = __builtin_amdgcn_mfma_f32_16x16x32_bf16(a, bb, a1[nt], 0, 0, 0);
            }
        }
    };
    auto GELU_ST = [&](int st, f32x4* a1) {
        u16* hd = &hb[st & 1][0];
#pragma unroll
        for (int nt = 0; nt < 4; nt++) {
            int fcol = wq * 64 + nt * 16 + l15;
#pragma unroll
            for (int j = 0; j < 4; j++) {
                int row = wr * 16 + l4 * 4 + j;       // 0..31
                float v = a1[nt][j] + b1v[nt];
                v = gelu_fast(v) * gw;
                hd[row * 256 + ((((fcol >> 3) ^ (row & 7)) << 3) | (fcol & 7))] = f2bf(v);
            }
        }
    };
    auto G2 = [&](int st, f32x4* a2) {
        const u16* hs = &hb[st & 1][0];
        int arow = wr * 16 + l15;                     // 0..31
        a2[0] = (f32x4){0.f, 0.f, 0.f, 0.f};
        a2[1] = (f32x4){0.f, 0.f, 0.f, 0.f};
#pragma unroll
        for (int kb = 0; kb < 8; kb++) {
            int fg = kb * 4 + l4;
            short8 a = *(const short8*)&hs[arow * 256 + ((fg ^ (arow & 7)) << 3)];
            a2[0] = __builtin_amdgcn_mfma_f32_16x16x32_bf16(a, w2f[0][kb], a2[0], 0, 0, 0);
            a2[1] = __builtin_amdgcn_mfma_f32_16x16x32_bf16(a, w2f[1][kb], a2[1], 0, 0, 0);
        }
    };
    auto YST = [&](int st, f32x4* a2) {
        const u16* xc = &xs[(st >> 1) & 1][0];
        u16* yb = y + xbase + (size_t)grp * 65536 + st * 4096;
#pragma unroll
        for (int n = 0; n < 2; n++) {
            int d = wq * 32 + n * 16 + l15;
#pragma unroll
            for (int j = 0; j < 4; j++) {
                int row = wr * 16 + l4 * 4 + j;       // 0..31
                int xrow = (st & 1) * 32 + row;
                float xr = bf2f(xc[xrow * 128 + ((((d >> 3) ^ (xrow & 7)) << 3) | (d & 7))]);
                yb[row * 128 + d] = f2bf(a2[n][j] + bcv[n] + xr);
            }
        }
    };

    // pipeline prologue: GEMM1(0) -> GELU -> hb[0]
    {
        f32x4 a1[4];
        G1(0, a1);
        GELU_ST(0, a1);
    }
    asm volatile("s_waitcnt lgkmcnt(0)" ::: "memory");
    __builtin_amdgcn_s_barrier();

    for (int st = 0; st < 16; ++st) {
        const bool stg = ((st & 1) == 0) && st >= 2 && st <= 12;
        if (stg) {   // stage tile T = st/2+1 into xs[T&1] (no readers this iter)
            int T = st / 2 + 1;
            if (XB) {
                const u16* xbp = (const u16*)xsrc_;
                gload_lds16(xbp + gbase + T * 8192 + t * 8, (char*)&xs[T & 1][0] + t * 16);
                gload_lds16(xbp + gbase + T * 8192 + 4096 + t * 8,
                            (char*)&xs[T & 1][0] + 8192 + t * 16);
            } else {
                const float* xf = (const float*)xsrc_;
#pragma unroll
                for (int p = 0; p < 4; p++) {
                    int elem = p * 2048 + t * 4;
                    int row = elem >> 7, col = elem & 127;
                    float4 v = *(const float4*)&xf[gbase + T * 8192 + elem];
                    ushort4v u;
                    u.x = f2bf(v.x); u.y = f2bf(v.y); u.z = f2bf(v.z); u.w = f2bf(v.w);
                    *(ushort4v*)((char*)&xs[T & 1][0] + row * 256 +
                                 (((col >> 3) ^ (row & 7)) << 4) + (col & 7) * 2) = u;
                }
            }
        }
        f32x4 a1n[4];
        if (st < 15) G1(st + 1, a1n);
        f32x4 a2[2];
        G2(st, a2);
        if (st < 15) GELU_ST(st + 1, a1n);   // VALU overlaps G2's MFMAs
        YST(st, a2);
        asm volatile("s_waitcnt lgkmcnt(0)" ::: "memory");
        if (stg && XB) asm volatile("s_waitcnt vmcnt(8)" ::: "memory");
        if (stg && !XB) asm volatile("s_waitcnt vmcnt(0)" ::: "memory");
        __builtin_amdgcn_s_barrier();
    }
}

// ---------------- Kernel 5: out = y @ w3^T + b3, 256^2 distributed-staging -
// 4 quadrant-phases/K-tile, barrier pairs; staging spread 1 region (2 loads)
// per phase: Bh1(tt+1)@P1, Ah1(tt+1)@P2 (-> other buf), Ah0(tt+2)@P3,
// Bh0(tt+2)@P4 (-> own buf). Uniform vmcnt(8) per phase-end proves the
// region staged 5 phases ago landed block-wide (wait-then-barrier). WAR per
// region verified: each staged region's readers drained >=1 barrier earlier.
#define BARX() do { asm volatile("" ::: "memory"); __builtin_amdgcn_s_barrier(); \
                    asm volatile("" ::: "memory"); } while (0)
#define WLGC(NSTR) do { asm volatile("s_waitcnt lgkmcnt(" NSTR ")" ::: "memory"); \
                        __builtin_amdgcn_sched_barrier(0); } while (0)
#define WVMC(NSTR) do { asm volatile("s_waitcnt vmcnt(" NSTR ")" ::: "memory"); \
                        __builtin_amdgcn_sched_barrier(0); } while (0)

#define DSA(mh, c) do { \
    const char* _ba = smem + (c) * 65536 + abase; \
    _Pragma("unroll") for (int mf = 0; mf < 4; mf++) \
    _Pragma("unroll") for (int kk = 0; kk < 2; kk++) \
        areg[mf][kk] = *(const short8*)(_ba + ((mh) * 4 + mf) * 2048 + kof[kk]); \
} while (0)

#define DSB(nh, c) do { \
    const char* _bb = smem + (c) * 65536 + bbase; \
    _Pragma("unroll") for (int nf = 0; nf < 2; nf++) \
    _Pragma("unroll") for (int kk = 0; kk < 2; kk++) \
        breg[(nh) * 2 + nf][kk] = *(const short8*)(_bb + ((nh) * 2 + nf) * 2048 + kof[kk]); \
} while (0)

#define MMAQ(mh, nh) do { \
    __builtin_amdgcn_s_setprio(1); \
    _Pragma("unroll") for (int mf = 0; mf < 4; mf++) \
    _Pragma("unroll") for (int nf = 0; nf < 2; nf++) \
    _Pragma("unroll") for (int kk = 0; kk < 2; kk++) \
        acc[(mh) * 4 + mf][(nh) * 2 + nf] = __builtin_amdgcn_mfma_f32_16x16x32_bf16( \
            areg[mf][kk], breg[(nh) * 2 + nf][kk], acc[(mh) * 4 + mf][(nh) * 2 + nf], 0, 0, 0); \
    __builtin_amdgcn_s_setprio(0); \
} while (0)

// op: 0=A(src yap, rows mrow0)  1=B(src wbp, rows nrow0); half h; K-tile kt
#define STG(op, c, h, kt) do { \
    const u16* _gs = (op) ? wbp : yap; \
    int _tr0 = (op) ? nrow0 : mrow0; \
    _Pragma("unroll") for (int p = 0; p < 2; p++) { \
        int _idx = p * 512 + t; \
        int _row = _idx >> 3; \
        int _gcol = (((_idx & 7) ^ (_row & 7)) << 3); \
        gload_lds16(_gs + (size_t)(_tr0 + (h) * 128 + _row) * 2048 + (kt) * 64 + _gcol, \
                    smem + (c) * 65536 + (op) * 32768 + (h) * 16384 + _idx * 16); \
    } \
} while (0)

__global__ __launch_bounds__(512, 2) void final_gemm256(const u16* __restrict__ yap,
                                                        const u16* __restrict__ wbp,
                                                        const float* __restrict__ b3,
                                                        float* __restrict__ out) {
    extern __shared__ char smem[];
    const int t = threadIdx.x;
    const int lane = t & 63, w = t >> 6;
    const int wm = w >> 2, wn = w & 3;
    const int l15 = lane & 15, l4 = lane >> 4, sx = lane & 7;

    // XCD swizzle: 512 wgs, 8 XCDs -> each XCD owns one 256-col panel
    int bid = blockIdx.x;
    int swz = (bid & 7) * 64 + (bid >> 3);
    int nblk = swz >> 6, mblk = swz & 63;
    const int mrow0 = mblk * 256;
    const int nrow0 = nblk * 256;

    const int abase = wm * 16384 + l15 * 128;
    const int bbase = 32768 + (wn >> 1) * 16384 + ((wn & 1) * 64 + l15) * 128;
    int kof[2];
#pragma unroll
    for (int kk = 0; kk < 2; kk++) kof[kk] = ((kk * 4 + l4) ^ sx) << 4;

    f32x4 acc[8][4];
#pragma unroll
    for (int m = 0; m < 8; m++)
#pragma unroll
        for (int n = 0; n < 4; n++) acc[m][n] = (f32x4){0.f, 0.f, 0.f, 0.f};
    short8 areg[4][2];
    short8 breg[4][2];

    // prologue: tile0 (Ah0,Ah1,Bh0,Bh1) then tile1 in drain order Ah0,Bh0,Bh1,Ah1
    STG(0, 0, 0, 0); STG(0, 0, 1, 0); STG(1, 0, 0, 0); STG(1, 0, 1, 0);
    STG(0, 1, 0, 1); STG(1, 1, 0, 1); STG(1, 1, 1, 1); STG(0, 1, 1, 1);
    WVMC("8");          // tile0's 8 landed
    BARX();

    for (int tt = 0; tt < 30; ++tt) {
        const int c = tt & 1;
        // P1: Q00 (A0,B0) ; stage Bh1 of tt+1 -> buf c^1
        DSA(0, c); DSB(0, c);
        if (tt >= 1) STG(1, c ^ 1, 1, tt + 1);
        WLGC("8");
        BARX(); WLGC("0"); MMAQ(0, 0);
        WVMC("8"); BARX();
        // P2: Q01 (A0,B1) ; stage Ah1 of tt+1 -> buf c^1
        DSB(1, c);
        if (tt >= 1) STG(0, c ^ 1, 1, tt + 1);
        BARX(); WLGC("0"); MMAQ(0, 1);
        WVMC("8"); BARX();
        // P3: Q10 (A1,B0) ; stage Ah0 of tt+2 -> buf c
        DSA(1, c);
        STG(0, c, 0, tt + 2);
        BARX(); WLGC("0"); MMAQ(1, 0);
        WVMC("8"); BARX();
        // P4: Q11 (A1,B1) ; stage Bh0 of tt+2 -> buf c
        STG(1, c, 0, tt + 2);
        BARX(); MMAQ(1, 1);
        WVMC("8"); BARX();
    }
    { // ---- tile 30 (c=0): stage only tile31 tail regions ----
        const int c = 0;
        DSA(0, c); DSB(0, c); STG(1, c ^ 1, 1, 31);
        WLGC("8"); BARX(); WLGC("0"); MMAQ(0, 0);
        WVMC("8"); BARX();
        DSB(1, c); STG(0, c ^ 1, 1, 31);
        BARX(); WLGC("0"); MMAQ(0, 1);
        WVMC("8"); BARX();
        DSA(1, c);
        BARX(); WLGC("0"); MMAQ(1, 0);
        WVMC("4"); BARX();           // drains 29P3/29P4 = Ah0/Bh0 of tile31
        BARX(); MMAQ(1, 1);
        WVMC("4"); BARX();
    }
    { // ---- tile 31 (c=1): no staging ----
        const int c = 1;
        DSA(0, c); DSB(0, c);
        WLGC("8"); BARX(); WLGC("0"); MMAQ(0, 0);
        WVMC("2"); BARX();           // drains 30P1 = Bh1 of tile31
        DSB(1, c);
        BARX(); WLGC("0"); MMAQ(0, 1);
        WVMC("0"); BARX();           // drains 30P2 = Ah1 of tile31
        DSA(1, c);
        BARX(); WLGC("0"); MMAQ(1, 0);
        BARX();
        MMAQ(1, 1);
    }

    // epilogue: bias + fp32 store
#pragma unroll
    for (int m = 0; m < 8; m++)
#pragma unroll
        for (int n = 0; n < 4; n++) {
            int col = nrow0 + wn * 64 + n * 16 + l15;
            float bias = b3[col];
            int row = mrow0 + wm * 128 + m * 16 + l4 * 4;
#pragma unroll
            for (int j = 0; j < 4; j++)
                out[(size_t)(row + j) * 2048 + col] = acc[m][n][j] + bias;
        }
}

// ---------------------------------------------------------------------------
extern "C" void kernel_launch(void* const* d_in, const int* in_sizes, int n_in,
                              void* d_out, int out_size, void* d_ws, size_t ws_size,
                              hipStream_t stream) {
    const float* x   = (const float*)d_in[0];
    const float* sw  = (const float*)d_in[1];
    const float* swb = (const float*)d_in[2];
    const float* w1  = (const float*)d_in[3];
    const float* b1  = (const float*)d_in[4];
    const float* w2  = (const float*)d_in[5];
    const float* b2  = (const float*)d_in[6];
    const float* w3  = (const float*)d_in[7];
    const float* b3  = (const float*)d_in[8];
    float* out = (float*)d_out;

    char* ws = (char*)d_ws;
    float* part = (float*)(ws + 0);                 // 128 KB
    float* gate = (float*)(ws + 131072);            // 64 B
    int*   idx  = (int*)(ws + 131136);              // 64 B
    float* bc   = (float*)(ws + 131200);            // 4 KB
    u16*   w1b  = (u16*)(ws + 262144);              // 256 KB (swizzled)
    u16*   w2b  = (u16*)(ws + 524288);              // 256 KB
    u16*   w3b  = (u16*)(ws + 786432);              // 8 MB
    u16*   y    = (u16*)(ws + 9175040);             // 64 MB
    u16*   xb   = (u16*)(ws + 76283904);            // 64 MB (swizzled bf16 x)
    const size_t need_xb = 143392768;
    const bool xbmode = ws_size >= need_xb;

    hipFuncSetAttribute((const void*)final_gemm256,
                        hipFuncAttributeMaxDynamicSharedMemorySize, 131072);

    if (xbmode)
        hipLaunchKernelGGL((router_partial<1>), dim3(NCHUNK), dim3(256), 0, stream, x, sw, part, xb);
    else
        hipLaunchKernelGGL((router_partial<0>), dim3(NCHUNK), dim3(256), 0, stream, x, sw, part, xb);
    hipLaunchKernelGGL(router_finish, dim3(1), dim3(128), 0, stream, part, swb, b2, gate, idx, bc);
    hipLaunchKernelGGL(convert_w12, dim3(256), dim3(256), 0, stream, w1, w2, w1b, w2b);
    hipLaunchKernelGGL(convert_w3, dim3(D_ * D_ / 1024), dim3(256), 0, stream, w3, w3b);
    if (xbmode)
        hipLaunchKernelGGL((mlp_kernel<1>), dim3(64, 8), dim3(512), 0, stream,
                           (const void*)xb, w1b, w2b, b1, gate, idx, bc, y);
    else
        hipLaunchKernelGGL((mlp_kernel<0>), dim3(64, 8), dim3(512), 0, stream,
                           (const void*)x, w1b, w2b, b1, gate, idx, bc, y);
    hipLaunchKernelGGL(final_gemm256, dim3(512), dim3(512), 131072, stream,
                       y, w3b, b3, out);
}

// Round 8
// 325.484 us; speedup vs baseline: 1.0287x; 1.0287x over previous
//
#include <hip/hip_runtime.h>
#include <math.h>

typedef unsigned short u16;
typedef unsigned int u32;
typedef __attribute__((ext_vector_type(8))) short short8;
typedef __attribute__((ext_vector_type(4))) float f32x4;
typedef __attribute__((ext_vector_type(4))) unsigned short ushort4v;

#define B_ 8
#define S_ 2048
#define D_ 2048
#define H_ 16
#define RLEN 4194304   // S_*D_ elems per batch sample
#define NCHUNK 512

static __device__ __forceinline__ u16 f2bf(float f) {
    union { float f; u32 u; } v; v.f = f;
    u32 r = v.u + 0x7fffu + ((v.u >> 16) & 1u);
    return (u16)(r >> 16);
}
static __device__ __forceinline__ float bf2f(u16 u) {
    union { u32 u; float f; } v; v.u = ((u32)u) << 16;
    return v.f;
}
// fast tanh-GELU (|err| <= ~3e-3 vs exact, within bf16 budget)
static __device__ __forceinline__ float gelu_fast(float v) {
    float z = 1.5957691216057308f * v * (1.0f + 0.044715f * v * v);
    float e = __expf(z);
    float r = __builtin_amdgcn_rcpf(e + 1.0f);
    return v * (1.0f - r);
}

typedef const __attribute__((address_space(1))) u32* gas1_t;
typedef __attribute__((address_space(3))) u32* las3_t;
static __device__ __forceinline__ void gload_lds16(const void* g, void* l) {
    __builtin_amdgcn_global_load_lds((gas1_t)g, (las3_t)l, 16, 0, 0);
}

// ---------------- Kernel 1: router partial dots (+ fused x->bf16 swizzled) --
// VGPR-trimmed: single rotating sv (one-ahead prefetch) instead of sv[8].
template<int XB>
__global__ __launch_bounds__(256, 3) void router_partial(const float* __restrict__ x,
                                                         const float* __restrict__ sw,
                                                         float* __restrict__ part,
                                                         u16* __restrict__ xb) {
    int c = blockIdx.x;
    int t = threadIdx.x;
    const int chunk = RLEN / NCHUNK;        // 8192
    int base = c * chunk;
    float acc[8][8];
#pragma unroll
    for (int b = 0; b < 8; b++)
#pragma unroll
        for (int e = 0; e < 8; e++) acc[b][e] = 0.f;

    for (int it = 0; it < chunk / (256 * 4); ++it) {   // 8 iterations
        int i = base + (it * 256 + t) * 4;
        float4 xv[8];
#pragma unroll
        for (int b = 0; b < 8; b++) xv[b] = *(const float4*)&x[(size_t)b * RLEN + i];
        if (XB) {
            int row = i >> 7, col = i & 127;
            int scol = (((col >> 3) ^ (row & 7)) << 3) | (col & 7);
#pragma unroll
            for (int b = 0; b < 8; b++) {
                ushort4v u;
                u.x = f2bf(xv[b].x); u.y = f2bf(xv[b].y);
                u.z = f2bf(xv[b].z); u.w = f2bf(xv[b].w);
                *(ushort4v*)&xb[(size_t)b * RLEN + (size_t)row * 128 + scol] = u;
            }
        }
        float4 sv = *(const float4*)&sw[i];
#pragma unroll
        for (int e = 0; e < 8; e++) {
            float4 svn;
            if (e < 7) svn = *(const float4*)&sw[(size_t)(e + 1) * RLEN + i];
#pragma unroll
            for (int b = 0; b < 8; b++)
                acc[b][e] += xv[b].x * sv.x + xv[b].y * sv.y +
                             xv[b].z * sv.z + xv[b].w * sv.w;
            sv = svn;
        }
    }

    __shared__ float red[4][64];
    int lane = t & 63, wv = t >> 6;
#pragma unroll
    for (int q = 0; q < 64; q++) {
        float v = acc[q >> 3][q & 7];
#pragma unroll
        for (int m = 32; m >= 1; m >>= 1) v += __shfl_xor(v, m, 64);
        if (lane == 0) red[wv][q] = v;
    }
    __syncthreads();
    if (t < 64) {
        float s = red[0][t] + red[1][t] + red[2][t] + red[3][t];
        part[(size_t)t * NCHUNK + c] = s;
    }
}

// ---------------- Kernel 2: reduce + softmax + top-2 + combined b2 bias ----
__global__ __launch_bounds__(128) void router_finish(const float* __restrict__ part,
                                                     const float* __restrict__ swb,
                                                     const float* __restrict__ b2,
                                                     float* __restrict__ gate,
                                                     int* __restrict__ idx,
                                                     float* __restrict__ bc) {
    int t = threadIdx.x;
    __shared__ float lg[64];
    __shared__ float sg[16];
    __shared__ int   si[16];
    if (t < 64) {
        float s = 0.f;
        for (int c = 0; c < NCHUNK; c++) s += part[(size_t)t * NCHUNK + c];
        lg[t] = s + swb[t & 7];
    }
    __syncthreads();
    if (t < 8) {
        int b = t;
        float m = -1e30f;
        for (int e = 0; e < 8; e++) m = fmaxf(m, lg[b * 8 + e]);
        float p[8]; float sum = 0.f;
        for (int e = 0; e < 8; e++) { p[e] = expf(lg[b * 8 + e] - m); sum += p[e]; }
        for (int e = 0; e < 8; e++) p[e] /= sum;
        int i1 = 0; float v1 = p[0];
        for (int e = 1; e < 8; e++) if (p[e] > v1) { v1 = p[e]; i1 = e; }
        int i2 = -1; float v2 = -1.f;
        for (int e = 0; e < 8; e++) if (e != i1 && p[e] > v2) { v2 = p[e]; i2 = e; }
        gate[b * 2 + 0] = v1; gate[b * 2 + 1] = v2;
        idx[b * 2 + 0] = i1;  idx[b * 2 + 1] = i2;
        sg[b * 2] = v1; sg[b * 2 + 1] = v2;
        si[b * 2] = i1; si[b * 2 + 1] = i2;
    }
    __syncthreads();
    for (int b = 0; b < 8; b++)
        bc[b * 128 + t] = sg[b * 2] * b2[si[b * 2] * 128 + t] +
                          sg[b * 2 + 1] * b2[si[b * 2 + 1] * 128 + t];
}

// ---------------- Kernel 3a: w1/w2 -> bf16 (w1 swizzled) -------------------
__global__ __launch_bounds__(256) void convert_w12(const float* __restrict__ w1,
                                                   const float* __restrict__ w2,
                                                   u16* __restrict__ w1b,
                                                   u16* __restrict__ w2b) {
    int i4 = (blockIdx.x * 256 + threadIdx.x) * 4;
    if (i4 < 131072) {
        int k = i4 & 127, f = (i4 >> 7) & 127;
        float4 v = *(const float4*)&w1[i4];
        int sc = ((((k >> 3) ^ (f & 7)) << 3) | (k & 7));
        ushort4v u;
        u.x = f2bf(v.x); u.y = f2bf(v.y); u.z = f2bf(v.z); u.w = f2bf(v.w);
        *(ushort4v*)&w1b[(i4 & ~127) + sc] = u;
    } else {
        int j = i4 - 131072;
        float4 v = *(const float4*)&w2[j];
        ushort4v u;
        u.x = f2bf(v.x); u.y = f2bf(v.y); u.z = f2bf(v.z); u.w = f2bf(v.w);
        *(ushort4v*)&w2b[j] = u;
    }
}

// ---------------- Kernel 3b: w3 -> bf16 ------------------------------------
__global__ __launch_bounds__(256) void convert_w3(const float* __restrict__ w3,
                                                  u16* __restrict__ w3b) {
    size_t i = ((size_t)blockIdx.x * 256 + threadIdx.x) * 4;
    float4 v = *(const float4*)&w3[i];
    u16* d = &w3b[i];
    d[0] = f2bf(v.x); d[1] = f2bf(v.y); d[2] = f2bf(v.z); d[3] = f2bf(v.w);
}

// ---------------- Kernel 4: expert MLP v4 — vectorized stores via ob -------
// Per iter: G1(st+1) || G2(st) || GELU(st+1) || OWRITE(st)->ob[st&1],
// then YSTV(st-1): ds_read_b128 ob[(st-1)&1] -> 16B coalesced global store.
// ONE barrier/iter. Staging loads issued before the store; vmcnt(1) drains
// exactly the 2 staging loads (in-order retirement) before the barrier.
template<int XB>
__global__ __launch_bounds__(512) void mlp_kernel(const void* __restrict__ xsrc_,
                                                  const u16* __restrict__ w1b,
                                                  const u16* __restrict__ w2b,
                                                  const float* __restrict__ b1,
                                                  const float* __restrict__ gate,
                                                  const int* __restrict__ idx,
                                                  const float* __restrict__ bc,
                                                  u16* __restrict__ y) {
    __shared__ __align__(16) u16 w1s[256 * 128];   // 64 KB (both experts)
    __shared__ __align__(16) u16 xs[2][64 * 128];  // 32 KB
    __shared__ __align__(16) u16 hb[2][32 * 256];  // 32 KB
    __shared__ __align__(16) u16 ob[2][32 * 128];  // 16 KB  (144 KB total)
    const int t = threadIdx.x, lane = t & 63, w = t >> 6;
    const int wr = w >> 2, wq = w & 3;
    const int l15 = lane & 15, l4 = lane >> 4;
    const int b = blockIdx.y, grp = blockIdx.x;
    const size_t xbase = (size_t)b * RLEN;
    const size_t gbase = xbase + (size_t)grp * 65536;
    const int e0 = idx[b * 2], e1 = idx[b * 2 + 1];
    const int slot = wq >> 1;
    const float gw = gate[b * 2 + slot];
    const float* b1p = b1 + (slot ? e1 : e0) * 128;

    float b1v[4];
#pragma unroll
    for (int nt = 0; nt < 4; nt++) b1v[nt] = b1p[(wq & 1) * 64 + nt * 16 + l15];
    float bcv[2];
#pragma unroll
    for (int n = 0; n < 2; n++) bcv[n] = bc[b * 128 + wq * 32 + n * 16 + l15];

    short8 w2f[2][8];
#pragma unroll
    for (int n = 0; n < 2; n++) {
        int d = wq * 32 + n * 16 + l15;
#pragma unroll
        for (int kb = 0; kb < 8; kb++) {
            int e = (kb >= 4) ? e1 : e0;
            int f = (kb & 3) * 32 + l4 * 8;
            w2f[n][kb] = *(const short8*)&w2b[((size_t)(e * 128 + d)) * 128 + f];
        }
    }

#pragma unroll
    for (int p = 0; p < 8; p++) {
        int elem = p * 4096 + t * 8;
        int frow = elem >> 7, col = elem & 127;
        int e = (frow >= 128) ? e1 : e0;
        gload_lds16(w1b + ((size_t)(e * 128 + (frow & 127))) * 128 + col,
                    (char*)w1s + elem * 2);
    }
    if (XB) {
        const u16* xbp = (const u16*)xsrc_;
#pragma unroll
        for (int T = 0; T < 2; T++) {
            gload_lds16(xbp + gbase + T * 8192 + t * 8, (char*)&xs[T][0] + t * 16);
            gload_lds16(xbp + gbase + T * 8192 + 4096 + t * 8,
                        (char*)&xs[T][0] + 8192 + t * 16);
        }
        asm volatile("s_waitcnt vmcnt(0)" ::: "memory");
    } else {
        const float* xf = (const float*)xsrc_;
#pragma unroll
        for (int T = 0; T < 2; T++)
#pragma unroll
            for (int p = 0; p < 4; p++) {
                int elem = p * 2048 + t * 4;
                int row = elem >> 7, col = elem & 127;
                float4 v = *(const float4*)&xf[gbase + T * 8192 + elem];
                ushort4v u;
                u.x = f2bf(v.x); u.y = f2bf(v.y); u.z = f2bf(v.z); u.w = f2bf(v.w);
                *(ushort4v*)((char*)&xs[T][0] + row * 256 +
                             (((col >> 3) ^ (row & 7)) << 4) + (col & 7) * 2) = u;
            }
        asm volatile("s_waitcnt vmcnt(0) lgkmcnt(0)" ::: "memory");
    }
    __builtin_amdgcn_s_barrier();

    auto G1 = [&](int st, f32x4* a1) {
        const u16* xc = &xs[(st >> 1) & 1][0];
        int rbase = (st & 1) * 32 + wr * 16 + l15;
#pragma unroll
        for (int nt = 0; nt < 4; nt++) a1[nt] = (f32x4){0.f, 0.f, 0.f, 0.f};
#pragma unroll
        for (int kb = 0; kb < 4; kb++) {
            int kg = kb * 4 + l4;
            short8 a = *(const short8*)&xc[rbase * 128 + ((kg ^ (rbase & 7)) << 3)];
#pragma unroll
            for (int nt = 0; nt < 4; nt++) {
                int fr = wq * 64 + nt * 16 + l15;
                short8 bb = *(const short8*)&w1s[fr * 128 + ((kg ^ (fr & 7)) << 3)];
                a1[nt] = __builtin_amdgcn_mfma_f32_16x16x32_bf16(a, bb, a1[nt], 0, 0, 0);
            }
        }
    };
    auto GELU_ST = [&](int st, f32x4* a1) {
        u16* hd = &hb[st & 1][0];
#pragma unroll
        for (int nt = 0; nt < 4; nt++) {
            int fcol = wq * 64 + nt * 16 + l15;
#pragma unroll
            for (int j = 0; j < 4; j++) {
                int row = wr * 16 + l4 * 4 + j;
                float v = a1[nt][j] + b1v[nt];
                v = gelu_fast(v) * gw;
                hd[row * 256 + ((((fcol >> 3) ^ (row & 7)) << 3) | (fcol & 7))] = f2bf(v);
            }
        }
    };
    auto G2 = [&](int st, f32x4* a2) {
        const u16* hs = &hb[st & 1][0];
        int arow = wr * 16 + l15;
        a2[0] = (f32x4){0.f, 0.f, 0.f, 0.f};
        a2[1] = (f32x4){0.f, 0.f, 0.f, 0.f};
#pragma unroll
        for (int kb = 0; kb < 8; kb++) {
            int fg = kb * 4 + l4;
            short8 a = *(const short8*)&hs[arow * 256 + ((fg ^ (arow & 7)) << 3)];
            a2[0] = __builtin_amdgcn_mfma_f32_16x16x32_bf16(a, w2f[0][kb], a2[0], 0, 0, 0);
            a2[1] = __builtin_amdgcn_mfma_f32_16x16x32_bf16(a, w2f[1][kb], a2[1], 0, 0, 0);
        }
    };
    auto OWRITE = [&](int st, f32x4* a2) {
        u16* od = &ob[st & 1][0];
        const u16* xc = &xs[(st >> 1) & 1][0];
#pragma unroll
        for (int n = 0; n < 2; n++) {
            int d = wq * 32 + n * 16 + l15;
#pragma unroll
            for (int j = 0; j < 4; j++) {
                int row = wr * 16 + l4 * 4 + j;
                int xrow = (st & 1) * 32 + row;
                float xr = bf2f(xc[xrow * 128 + ((((d >> 3) ^ (xrow & 7)) << 3) | (d & 7))]);
                od[row * 128 + (d ^ ((row & 7) << 3))] = f2bf(a2[n][j] + bcv[n] + xr);
            }
        }
    };
    auto YSTV = [&](int st) {
        int row = t >> 4;          // 0..31
        int cg = t & 15;
        const u16* os = &ob[st & 1][0];
        short8 v = *(const short8*)&os[row * 128 + ((cg ^ (row & 7)) << 3)];
        u16* yb = y + xbase + (size_t)grp * 65536 + st * 4096;
        *(short8*)&yb[row * 128 + cg * 8] = v;
    };

    // prologue: GEMM1(0) -> GELU -> hb[0]
    {
        f32x4 a1[4];
        G1(0, a1);
        GELU_ST(0, a1);
    }
    asm volatile("s_waitcnt lgkmcnt(0)" ::: "memory");
    __builtin_amdgcn_s_barrier();

    for (int st = 0; st < 17; ++st) {
        const bool stg = (st < 16) && ((st & 1) == 0) && st >= 2 && st <= 12;
        if (st < 16) {
            f32x4 a1n[4];
            if (st < 15) G1(st + 1, a1n);
            f32x4 a2[2];
            G2(st, a2);
            if (st < 15) GELU_ST(st + 1, a1n);
            OWRITE(st, a2);
        }
        if (stg) {   // stage tile T = st/2+1 into xs[T&1] BEFORE the store
            int T = st / 2 + 1;
            if (XB) {
                const u16* xbp = (const u16*)xsrc_;
                gload_lds16(xbp + gbase + T * 8192 + t * 8, (char*)&xs[T & 1][0] + t * 16);
                gload_lds16(xbp + gbase + T * 8192 + 4096 + t * 8,
                            (char*)&xs[T & 1][0] + 8192 + t * 16);
            } else {
                const float* xf = (const float*)xsrc_;
#pragma unroll
                for (int p = 0; p < 4; p++) {
                    int elem = p * 2048 + t * 4;
                    int row = elem >> 7, col = elem & 127;
                    float4 v = *(const float4*)&xf[gbase + T * 8192 + elem];
                    ushort4v u;
                    u.x = f2bf(v.x); u.y = f2bf(v.y); u.z = f2bf(v.z); u.w = f2bf(v.w);
                    *(ushort4v*)((char*)&xs[T & 1][0] + row * 256 +
                                 (((col >> 3) ^ (row & 7)) << 4) + (col & 7) * 2) = u;
                }
            }
        }
        if (st >= 1) YSTV(st - 1);
        asm volatile("s_waitcnt lgkmcnt(0)" ::: "memory");
        if (stg && XB) asm volatile("s_waitcnt vmcnt(1)" ::: "memory");
        if (st < 16) __builtin_amdgcn_s_barrier();
    }
}

// ---------------- Kernel 5: out = y @ w3^T + b3, 256^2 pipelined (R6) ------
#define BARX() do { asm volatile("" ::: "memory"); __builtin_amdgcn_s_barrier(); \
                    asm volatile("" ::: "memory"); } while (0)

#define WLG(NSTR) do { asm volatile("s_waitcnt lgkmcnt(" NSTR ")" ::: "memory"); \
                       __builtin_amdgcn_sched_barrier(0); } while (0)

#define DSA(mh, c) do { \
    const char* _ba = smem + (c) * 65536 + abase; \
    _Pragma("unroll") for (int mf = 0; mf < 4; mf++) \
    _Pragma("unroll") for (int kk = 0; kk < 2; kk++) \
        areg[mf][kk] = *(const short8*)(_ba + ((mh) * 4 + mf) * 2048 + kof[kk]); \
} while (0)

#define DSB(nh, c) do { \
    const char* _bb = smem + (c) * 65536 + bbase; \
    _Pragma("unroll") for (int nf = 0; nf < 2; nf++) \
    _Pragma("unroll") for (int kk = 0; kk < 2; kk++) \
        breg[(nh) * 2 + nf][kk] = *(const short8*)(_bb + ((nh) * 2 + nf) * 2048 + kof[kk]); \
} while (0)

#define MMAQ(mh, nh) do { \
    __builtin_amdgcn_s_setprio(1); \
    _Pragma("unroll") for (int mf = 0; mf < 4; mf++) \
    _Pragma("unroll") for (int nf = 0; nf < 2; nf++) \
    _Pragma("unroll") for (int kk = 0; kk < 2; kk++) \
        acc[(mh) * 4 + mf][(nh) * 2 + nf] = __builtin_amdgcn_mfma_f32_16x16x32_bf16( \
            areg[mf][kk], breg[(nh) * 2 + nf][kk], acc[(mh) * 4 + mf][(nh) * 2 + nf], 0, 0, 0); \
    __builtin_amdgcn_s_setprio(0); \
} while (0)

#define STG(op, c, h, kt) do { \
    const u16* _gs = (op) ? wbp : yap; \
    int _tr0 = (op) ? nrow0 : mrow0; \
    _Pragma("unroll") for (int p = 0; p < 2; p++) { \
        int _idx = p * 512 + t; \
        int _row = _idx >> 3; \
        int _gcol = (((_idx & 7) ^ (_row & 7)) << 3); \
        gload_lds16(_gs + (size_t)(_tr0 + (h) * 128 + _row) * 2048 + (kt) * 64 + _gcol, \
                    smem + (c) * 65536 + (op) * 32768 + (h) * 16384 + _idx * 16); \
    } \
} while (0)

__global__ __launch_bounds__(512, 2) void final_gemm256(const u16* __restrict__ yap,
                                                        const u16* __restrict__ wbp,
                                                        const float* __restrict__ b3,
                                                        float* __restrict__ out) {
    extern __shared__ char smem[];
    const int t = threadIdx.x;
    const int lane = t & 63, w = t >> 6;
    const int wm = w >> 2, wn = w & 3;
    const int l15 = lane & 15, l4 = lane >> 4, sx = lane & 7;

    int bid = blockIdx.x;
    int swz = (bid & 7) * 64 + (bid >> 3);
    int nblk = swz >> 6, mblk = swz & 63;
    const int mrow0 = mblk * 256;
    const int nrow0 = nblk * 256;

    const int abase = wm * 16384 + l15 * 128;
    const int bbase = 32768 + (wn >> 1) * 16384 + ((wn & 1) * 64 + l15) * 128;
    int kof[2];
#pragma unroll
    for (int kk = 0; kk < 2; kk++) kof[kk] = ((kk * 4 + l4) ^ sx) << 4;

    f32x4 acc[8][4];
#pragma unroll
    for (int m = 0; m < 8; m++)
#pragma unroll
        for (int n = 0; n < 4; n++) acc[m][n] = (f32x4){0.f, 0.f, 0.f, 0.f};
    short8 areg[4][2];
    short8 breg[4][2];

    STG(0, 0, 0, 0); STG(0, 0, 1, 0); STG(1, 0, 0, 0); STG(1, 0, 1, 0);
    STG(0, 1, 0, 1); STG(0, 1, 1, 1); STG(1, 1, 0, 1); STG(1, 1, 1, 1);
    asm volatile("s_waitcnt vmcnt(8)" ::: "memory");
    BARX();
    DSA(0, 0); DSB(0, 0); DSB(1, 0);

    for (int it2 = 0; it2 < 16; ++it2) {
#pragma unroll
        for (int c = 0; c < 2; ++c) {
            const int tt = 2 * it2 + c;
            WLG("4");  MMAQ(0, 0);
            WLG("0");  MMAQ(0, 1);
            DSA(1, c);
            WLG("0");  MMAQ(1, 0);
            asm volatile("s_waitcnt vmcnt(0)" ::: "memory");
            BARX();
            if (tt < 30) { STG(0, c, 0, tt + 2); STG(0, c, 1, tt + 2);
                           STG(1, c, 0, tt + 2); STG(1, c, 1, tt + 2); }
            MMAQ(1, 1);
            if (tt < 31) { DSA(0, c ^ 1); DSB(0, c ^ 1); DSB(1, c ^ 1); }
        }
    }

#pragma unroll
    for (int m = 0; m < 8; m++)
#pragma unroll
        for (int n = 0; n < 4; n++) {
            int col = nrow0 + wn * 64 + n * 16 + l15;
            float bias = b3[col];
            int row = mrow0 + wm * 128 + m * 16 + l4 * 4;
#pragma unroll
            for (int j = 0; j < 4; j++)
                out[(size_t)(row + j) * 2048 + col] = acc[m][n][j] + bias;
        }
}

// ---------------------------------------------------------------------------
extern "C" void kernel_launch(void* const* d_in, const int* in_sizes, int n_in,
                              void* d_out, int out_size, void* d_ws, size_t ws_size,
                              hipStream_t stream) {
    const float* x   = (const float*)d_in[0];
    const float* sw  = (const float*)d_in[1];
    const float* swb = (const float*)d_in[2];
    const float* w1  = (const float*)d_in[3];
    const float* b1  = (const float*)d_in[4];
    const float* w2  = (const float*)d_in[5];
    const float* b2  = (const float*)d_in[6];
    const float* w3  = (const float*)d_in[7];
    const float* b3  = (const float*)d_in[8];
    float* out = (float*)d_out;

    char* ws = (char*)d_ws;
    float* part = (float*)(ws + 0);                 // 128 KB
    float* gate = (float*)(ws + 131072);            // 64 B
    int*   idx  = (int*)(ws + 131136);              // 64 B
    float* bc   = (float*)(ws + 131200);            // 4 KB
    u16*   w1b  = (u16*)(ws + 262144);              // 256 KB (swizzled)
    u16*   w2b  = (u16*)(ws + 524288);              // 256 KB
    u16*   w3b  = (u16*)(ws + 786432);              // 8 MB
    u16*   y    = (u16*)(ws + 9175040);             // 64 MB
    u16*   xb   = (u16*)(ws + 76283904);            // 64 MB (swizzled bf16 x)
    const size_t need_xb = 143392768;
    const bool xbmode = ws_size >= need_xb;

    hipFuncSetAttribute((const void*)final_gemm256,
                        hipFuncAttributeMaxDynamicSharedMemorySize, 131072);

    if (xbmode)
        hipLaunchKernelGGL((router_partial<1>), dim3(NCHUNK), dim3(256), 0, stream, x, sw, part, xb);
    else
        hipLaunchKernelGGL((router_partial<0>), dim3(NCHUNK), dim3(256), 0, stream, x, sw, part, xb);
    hipLaunchKernelGGL(router_finish, dim3(1), dim3(128), 0, stream, part, swb, b2, gate, idx, bc);
    hipLaunchKernelGGL(convert_w12, dim3(256), dim3(256), 0, stream, w1, w2, w1b, w2b);
    hipLaunchKernelGGL(convert_w3, dim3(D_ * D_ / 1024), dim3(256), 0, stream, w3, w3b);
    if (xbmode)
        hipLaunchKernelGGL((mlp_kernel<1>), dim3(64, 8), dim3(512), 0, stream,
                           (const void*)xb, w1b, w2b, b1, gate, idx, bc, y);
    else
        hipLaunchKernelGGL((mlp_kernel<0>), dim3(64, 8), dim3(512), 0, stream,
                           (const void*)x, w1b, w2b, b1, gate, idx, bc, y);
    hipLaunchKernelGGL(final_gemm256, dim3(512), dim3(512), 131072, stream,
                       y, w3b, b3, out);
}

// Round 10
// 313.622 us; speedup vs baseline: 1.0676x; 1.0378x over previous
//
#include <hip/hip_runtime.h>
#include <math.h>

typedef unsigned short u16;
typedef unsigned int u32;
typedef __attribute__((ext_vector_type(8))) short short8;
typedef __attribute__((ext_vector_type(4))) float f32x4;
typedef __attribute__((ext_vector_type(4))) unsigned short ushort4v;

#define B_ 8
#define S_ 2048
#define D_ 2048
#define H_ 16
#define RLEN 4194304   // S_*D_ elems per batch sample
#define NCHUNK 512

static __device__ __forceinline__ u16 f2bf(float f) {
    union { float f; u32 u; } v; v.f = f;
    u32 r = v.u + 0x7fffu + ((v.u >> 16) & 1u);
    return (u16)(r >> 16);
}
static __device__ __forceinline__ float bf2f(u16 u) {
    union { u32 u; float f; } v; v.u = ((u32)u) << 16;
    return v.f;
}
// fast tanh-GELU (|err| <= ~3e-3 vs exact, within bf16 budget)
static __device__ __forceinline__ float gelu_fast(float v) {
    float z = 1.5957691216057308f * v * (1.0f + 0.044715f * v * v);
    float e = __expf(z);
    float r = __builtin_amdgcn_rcpf(e + 1.0f);
    return v * (1.0f - r);
}
// non-temporal float4 load via clang ext-vector (HIP_vector_type not accepted)
static __device__ __forceinline__ f32x4 ntload4(const float* p) {
    return __builtin_nontemporal_load((const f32x4*)p);
}

typedef const __attribute__((address_space(1))) u32* gas1_t;
typedef __attribute__((address_space(3))) u32* las3_t;
static __device__ __forceinline__ void gload_lds16(const void* g, void* l) {
    __builtin_amdgcn_global_load_lds((gas1_t)g, (las3_t)l, 16, 0, 0);
}

// ---------------- Kernel 1: router partial dots (+ fused x->bf16 swizzled) --
// nt-loads on x/sw: both are read-once streams; keep L3 clean for xb.
template<int XB>
__global__ __launch_bounds__(256, 3) void router_partial(const float* __restrict__ x,
                                                         const float* __restrict__ sw,
                                                         float* __restrict__ part,
                                                         u16* __restrict__ xb) {
    int c = blockIdx.x;
    int t = threadIdx.x;
    const int chunk = RLEN / NCHUNK;        // 8192
    int base = c * chunk;
    float acc[8][8];
#pragma unroll
    for (int b = 0; b < 8; b++)
#pragma unroll
        for (int e = 0; e < 8; e++) acc[b][e] = 0.f;

    for (int it = 0; it < chunk / (256 * 4); ++it) {   // 8 iterations
        int i = base + (it * 256 + t) * 4;
        f32x4 xv[8];
#pragma unroll
        for (int b = 0; b < 8; b++) xv[b] = ntload4(&x[(size_t)b * RLEN + i]);
        if (XB) {
            int row = i >> 7, col = i & 127;
            int scol = (((col >> 3) ^ (row & 7)) << 3) | (col & 7);
#pragma unroll
            for (int b = 0; b < 8; b++) {
                ushort4v u;
                u.x = f2bf(xv[b].x); u.y = f2bf(xv[b].y);
                u.z = f2bf(xv[b].z); u.w = f2bf(xv[b].w);
                *(ushort4v*)&xb[(size_t)b * RLEN + (size_t)row * 128 + scol] = u;
            }
        }
        f32x4 sv = ntload4(&sw[i]);
#pragma unroll
        for (int e = 0; e < 8; e++) {
            f32x4 svn;
            if (e < 7) svn = ntload4(&sw[(size_t)(e + 1) * RLEN + i]);
#pragma unroll
            for (int b = 0; b < 8; b++)
                acc[b][e] += xv[b].x * sv.x + xv[b].y * sv.y +
                             xv[b].z * sv.z + xv[b].w * sv.w;
            sv = svn;
        }
    }

    __shared__ float red[4][64];
    int lane = t & 63, wv = t >> 6;
#pragma unroll
    for (int q = 0; q < 64; q++) {
        float v = acc[q >> 3][q & 7];
#pragma unroll
        for (int m = 32; m >= 1; m >>= 1) v += __shfl_xor(v, m, 64);
        if (lane == 0) red[wv][q] = v;
    }
    __syncthreads();
    if (t < 64) {
        float s = red[0][t] + red[1][t] + red[2][t] + red[3][t];
        part[(size_t)t * NCHUNK + c] = s;
    }
}

// ---------------- Kernel 2: reduce + softmax + top-2 + combined b2 bias ----
__global__ __launch_bounds__(128) void router_finish(const float* __restrict__ part,
                                                     const float* __restrict__ swb,
                                                     const float* __restrict__ b2,
                                                     float* __restrict__ gate,
                                                     int* __restrict__ idx,
                                                     float* __restrict__ bc) {
    int t = threadIdx.x;
    __shared__ float lg[64];
    __shared__ float sg[16];
    __shared__ int   si[16];
    if (t < 64) {
        float s = 0.f;
        for (int c = 0; c < NCHUNK; c++) s += part[(size_t)t * NCHUNK + c];
        lg[t] = s + swb[t & 7];
    }
    __syncthreads();
    if (t < 8) {
        int b = t;
        float m = -1e30f;
        for (int e = 0; e < 8; e++) m = fmaxf(m, lg[b * 8 + e]);
        float p[8]; float sum = 0.f;
        for (int e = 0; e < 8; e++) { p[e] = expf(lg[b * 8 + e] - m); sum += p[e]; }
        for (int e = 0; e < 8; e++) p[e] /= sum;
        int i1 = 0; float v1 = p[0];
        for (int e = 1; e < 8; e++) if (p[e] > v1) { v1 = p[e]; i1 = e; }
        int i2 = -1; float v2 = -1.f;
        for (int e = 0; e < 8; e++) if (e != i1 && p[e] > v2) { v2 = p[e]; i2 = e; }
        gate[b * 2 + 0] = v1; gate[b * 2 + 1] = v2;
        idx[b * 2 + 0] = i1;  idx[b * 2 + 1] = i2;
        sg[b * 2] = v1; sg[b * 2 + 1] = v2;
        si[b * 2] = i1; si[b * 2 + 1] = i2;
    }
    __syncthreads();
    for (int b = 0; b < 8; b++)
        bc[b * 128 + t] = sg[b * 2] * b2[si[b * 2] * 128 + t] +
                          sg[b * 2 + 1] * b2[si[b * 2 + 1] * 128 + t];
}

// ---------------- Kernel 3a: w1/w2 -> bf16 (w1 swizzled) -------------------
__global__ __launch_bounds__(256) void convert_w12(const float* __restrict__ w1,
                                                   const float* __restrict__ w2,
                                                   u16* __restrict__ w1b,
                                                   u16* __restrict__ w2b) {
    int i4 = (blockIdx.x * 256 + threadIdx.x) * 4;
    if (i4 < 131072) {
        int k = i4 & 127, f = (i4 >> 7) & 127;
        float4 v = *(const float4*)&w1[i4];
        int sc = ((((k >> 3) ^ (f & 7)) << 3) | (k & 7));
        ushort4v u;
        u.x = f2bf(v.x); u.y = f2bf(v.y); u.z = f2bf(v.z); u.w = f2bf(v.w);
        *(ushort4v*)&w1b[(i4 & ~127) + sc] = u;
    } else {
        int j = i4 - 131072;
        float4 v = *(const float4*)&w2[j];
        ushort4v u;
        u.x = f2bf(v.x); u.y = f2bf(v.y); u.z = f2bf(v.z); u.w = f2bf(v.w);
        *(ushort4v*)&w2b[j] = u;
    }
}

// ---------------- Kernel 3b: w3 -> bf16 ------------------------------------
__global__ __launch_bounds__(256) void convert_w3(const float* __restrict__ w3,
                                                  u16* __restrict__ w3b) {
    size_t i = ((size_t)blockIdx.x * 256 + threadIdx.x) * 4;
    float4 v = *(const float4*)&w3[i];
    u16* d = &w3b[i];
    d[0] = f2bf(v.x); d[1] = f2bf(v.y); d[2] = f2bf(v.z); d[3] = f2bf(v.w);
}

// ---------------- Kernel 4: expert MLP v4 — vectorized stores via ob -------
template<int XB>
__global__ __launch_bounds__(512) void mlp_kernel(const void* __restrict__ xsrc_,
                                                  const u16* __restrict__ w1b,
                                                  const u16* __restrict__ w2b,
                                                  const float* __restrict__ b1,
                                                  const float* __restrict__ gate,
                                                  const int* __restrict__ idx,
                                                  const float* __restrict__ bc,
                                                  u16* __restrict__ y) {
    __shared__ __align__(16) u16 w1s[256 * 128];   // 64 KB (both experts)
    __shared__ __align__(16) u16 xs[2][64 * 128];  // 32 KB
    __shared__ __align__(16) u16 hb[2][32 * 256];  // 32 KB
    __shared__ __align__(16) u16 ob[2][32 * 128];  // 16 KB  (144 KB total)
    const int t = threadIdx.x, lane = t & 63, w = t >> 6;
    const int wr = w >> 2, wq = w & 3;
    const int l15 = lane & 15, l4 = lane >> 4;
    const int b = blockIdx.y, grp = blockIdx.x;
    const size_t xbase = (size_t)b * RLEN;
    const size_t gbase = xbase + (size_t)grp * 65536;
    const int e0 = idx[b * 2], e1 = idx[b * 2 + 1];
    const int slot = wq >> 1;
    const float gw = gate[b * 2 + slot];
    const float* b1p = b1 + (slot ? e1 : e0) * 128;

    float b1v[4];
#pragma unroll
    for (int nt = 0; nt < 4; nt++) b1v[nt] = b1p[(wq & 1) * 64 + nt * 16 + l15];
    float bcv[2];
#pragma unroll
    for (int n = 0; n < 2; n++) bcv[n] = bc[b * 128 + wq * 32 + n * 16 + l15];

    short8 w2f[2][8];
#pragma unroll
    for (int n = 0; n < 2; n++) {
        int d = wq * 32 + n * 16 + l15;
#pragma unroll
        for (int kb = 0; kb < 8; kb++) {
            int e = (kb >= 4) ? e1 : e0;
            int f = (kb & 3) * 32 + l4 * 8;
            w2f[n][kb] = *(const short8*)&w2b[((size_t)(e * 128 + d)) * 128 + f];
        }
    }

#pragma unroll
    for (int p = 0; p < 8; p++) {
        int elem = p * 4096 + t * 8;
        int frow = elem >> 7, col = elem & 127;
        int e = (frow >= 128) ? e1 : e0;
        gload_lds16(w1b + ((size_t)(e * 128 + (frow & 127))) * 128 + col,
                    (char*)w1s + elem * 2);
    }
    if (XB) {
        const u16* xbp = (const u16*)xsrc_;
#pragma unroll
        for (int T = 0; T < 2; T++) {
            gload_lds16(xbp + gbase + T * 8192 + t * 8, (char*)&xs[T][0] + t * 16);
            gload_lds16(xbp + gbase + T * 8192 + 4096 + t * 8,
                        (char*)&xs[T][0] + 8192 + t * 16);
        }
        asm volatile("s_waitcnt vmcnt(0)" ::: "memory");
    } else {
        const float* xf = (const float*)xsrc_;
#pragma unroll
        for (int T = 0; T < 2; T++)
#pragma unroll
            for (int p = 0; p < 4; p++) {
                int elem = p * 2048 + t * 4;
                int row = elem >> 7, col = elem & 127;
                float4 v = *(const float4*)&xf[gbase + T * 8192 + elem];
                ushort4v u;
                u.x = f2bf(v.x); u.y = f2bf(v.y); u.z = f2bf(v.z); u.w = f2bf(v.w);
                *(ushort4v*)((char*)&xs[T][0] + row * 256 +
                             (((col >> 3) ^ (row & 7)) << 4) + (col & 7) * 2) = u;
            }
        asm volatile("s_waitcnt vmcnt(0) lgkmcnt(0)" ::: "memory");
    }
    __builtin_amdgcn_s_barrier();

    auto G1 = [&](int st, f32x4* a1) {
        const u16* xc = &xs[(st >> 1) & 1][0];
        int rbase = (st & 1) * 32 + wr * 16 + l15;
#pragma unroll
        for (int nt = 0; nt < 4; nt++) a1[nt] = (f32x4){0.f, 0.f, 0.f, 0.f};
#pragma unroll
        for (int kb = 0; kb < 4; kb++) {
            int kg = kb * 4 + l4;
            short8 a = *(const short8*)&xc[rbase * 128 + ((kg ^ (rbase & 7)) << 3)];
#pragma unroll
            for (int nt = 0; nt < 4; nt++) {
                int fr = wq * 64 + nt * 16 + l15;
                short8 bb = *(const short8*)&w1s[fr * 128 + ((kg ^ (fr & 7)) << 3)];
                a1[nt] = __builtin_amdgcn_mfma_f32_16x16x32_bf16(a, bb, a1[nt], 0, 0, 0);
            }
        }
    };
    auto GELU_ST = [&](int st, f32x4* a1) {
        u16* hd = &hb[st & 1][0];
#pragma unroll
        for (int nt = 0; nt < 4; nt++) {
            int fcol = wq * 64 + nt * 16 + l15;
#pragma unroll
            for (int j = 0; j < 4; j++) {
                int row = wr * 16 + l4 * 4 + j;
                float v = a1[nt][j] + b1v[nt];
                v = gelu_fast(v) * gw;
                hd[row * 256 + ((((fcol >> 3) ^ (row & 7)) << 3) | (fcol & 7))] = f2bf(v);
            }
        }
    };
    auto G2 = [&](int st, f32x4* a2) {
        const u16* hs = &hb[st & 1][0];
        int arow = wr * 16 + l15;
        a2[0] = (f32x4){0.f, 0.f, 0.f, 0.f};
        a2[1] = (f32x4){0.f, 0.f, 0.f, 0.f};
#pragma unroll
        for (int kb = 0; kb < 8; kb++) {
            int fg = kb * 4 + l4;
            short8 a = *(const short8*)&hs[arow * 256 + ((fg ^ (arow & 7)) << 3)];
            a2[0] = __builtin_amdgcn_mfma_f32_16x16x32_bf16(a, w2f[0][kb], a2[0], 0, 0, 0);
            a2[1] = __builtin_amdgcn_mfma_f32_16x16x32_bf16(a, w2f[1][kb], a2[1], 0, 0, 0);
        }
    };
    auto OWRITE = [&](int st, f32x4* a2) {
        u16* od = &ob[st & 1][0];
        const u16* xc = &xs[(st >> 1) & 1][0];
#pragma unroll
        for (int n = 0; n < 2; n++) {
            int d = wq * 32 + n * 16 + l15;
#pragma unroll
            for (int j = 0; j < 4; j++) {
                int row = wr * 16 + l4 * 4 + j;
                int xrow = (st & 1) * 32 + row;
                float xr = bf2f(xc[xrow * 128 + ((((d >> 3) ^ (xrow & 7)) << 3) | (d & 7))]);
                od[row * 128 + (d ^ ((row & 7) << 3))] = f2bf(a2[n][j] + bcv[n] + xr);
            }
        }
    };
    auto YSTV = [&](int st) {
        int row = t >> 4;
        int cg = t & 15;
        const u16* os = &ob[st & 1][0];
        short8 v = *(const short8*)&os[row * 128 + ((cg ^ (row & 7)) << 3)];
        u16* yb = y + xbase + (size_t)grp * 65536 + st * 4096;
        *(short8*)&yb[row * 128 + cg * 8] = v;
    };

    {
        f32x4 a1[4];
        G1(0, a1);
        GELU_ST(0, a1);
    }
    asm volatile("s_waitcnt lgkmcnt(0)" ::: "memory");
    __builtin_amdgcn_s_barrier();

    for (int st = 0; st < 17; ++st) {
        const bool stg = (st < 16) && ((st & 1) == 0) && st >= 2 && st <= 12;
        if (st < 16) {
            f32x4 a1n[4];
            if (st < 15) G1(st + 1, a1n);
            f32x4 a2[2];
            G2(st, a2);
            if (st < 15) GELU_ST(st + 1, a1n);
            OWRITE(st, a2);
        }
        if (stg) {
            int T = st / 2 + 1;
            if (XB) {
                const u16* xbp = (const u16*)xsrc_;
                gload_lds16(xbp + gbase + T * 8192 + t * 8, (char*)&xs[T & 1][0] + t * 16);
                gload_lds16(xbp + gbase + T * 8192 + 4096 + t * 8,
                            (char*)&xs[T & 1][0] + 8192 + t * 16);
            } else {
                const float* xf = (const float*)xsrc_;
#pragma unroll
                for (int p = 0; p < 4; p++) {
                    int elem = p * 2048 + t * 4;
                    int row = elem >> 7, col = elem & 127;
                    float4 v = *(const float4*)&xf[gbase + T * 8192 + elem];
                    ushort4v u;
                    u.x = f2bf(v.x); u.y = f2bf(v.y); u.z = f2bf(v.z); u.w = f2bf(v.w);
                    *(ushort4v*)((char*)&xs[T & 1][0] + row * 256 +
                                 (((col >> 3) ^ (row & 7)) << 4) + (col & 7) * 2) = u;
                }
            }
        }
        if (st >= 1) YSTV(st - 1);
        asm volatile("s_waitcnt lgkmcnt(0)" ::: "memory");
        if (stg && XB) asm volatile("s_waitcnt vmcnt(1)" ::: "memory");
        if (st < 16) __builtin_amdgcn_s_barrier();
    }
}

// ---------------- Kernel 5: out = y @ w3^T + b3, 256^2 pipelined (R6) ------
// Epilogue uses NON-TEMPORAL stores: out (128MB fp32) is never re-read; nt
// keeps it from evicting y (64MB) from L3 between the 8 XCD re-reads.
#define BARX() do { asm volatile("" ::: "memory"); __builtin_amdgcn_s_barrier(); \
                    asm volatile("" ::: "memory"); } while (0)

#define WLG(NSTR) do { asm volatile("s_waitcnt lgkmcnt(" NSTR ")" ::: "memory"); \
                       __builtin_amdgcn_sched_barrier(0); } while (0)

#define DSA(mh, c) do { \
    const char* _ba = smem + (c) * 65536 + abase; \
    _Pragma("unroll") for (int mf = 0; mf < 4; mf++) \
    _Pragma("unroll") for (int kk = 0; kk < 2; kk++) \
        areg[mf][kk] = *(const short8*)(_ba + ((mh) * 4 + mf) * 2048 + kof[kk]); \
} while (0)

#define DSB(nh, c) do { \
    const char* _bb = smem + (c) * 65536 + bbase; \
    _Pragma("unroll") for (int nf = 0; nf < 2; nf++) \
    _Pragma("unroll") for (int kk = 0; kk < 2; kk++) \
        breg[(nh) * 2 + nf][kk] = *(const short8*)(_bb + ((nh) * 2 + nf) * 2048 + kof[kk]); \
} while (0)

#define MMAQ(mh, nh) do { \
    __builtin_amdgcn_s_setprio(1); \
    _Pragma("unroll") for (int mf = 0; mf < 4; mf++) \
    _Pragma("unroll") for (int nf = 0; nf < 2; nf++) \
    _Pragma("unroll") for (int kk = 0; kk < 2; kk++) \
        acc[(mh) * 4 + mf][(nh) * 2 + nf] = __builtin_amdgcn_mfma_f32_16x16x32_bf16( \
            areg[mf][kk], breg[(nh) * 2 + nf][kk], acc[(mh) * 4 + mf][(nh) * 2 + nf], 0, 0, 0); \
    __builtin_amdgcn_s_setprio(0); \
} while (0)

#define STG(op, c, h, kt) do { \
    const u16* _gs = (op) ? wbp : yap; \
    int _tr0 = (op) ? nrow0 : mrow0; \
    _Pragma("unroll") for (int p = 0; p < 2; p++) { \
        int _idx = p * 512 + t; \
        int _row = _idx >> 3; \
        int _gcol = (((_idx & 7) ^ (_row & 7)) << 3); \
        gload_lds16(_gs + (size_t)(_tr0 + (h) * 128 + _row) * 2048 + (kt) * 64 + _gcol, \
                    smem + (c) * 65536 + (op) * 32768 + (h) * 16384 + _idx * 16); \
    } \
} while (0)

__global__ __launch_bounds__(512, 2) void final_gemm256(const u16* __restrict__ yap,
                                                        const u16* __restrict__ wbp,
                                                        const float* __restrict__ b3,
                                                        float* __restrict__ out) {
    extern __shared__ char smem[];
    const int t = threadIdx.x;
    const int lane = t & 63, w = t >> 6;
    const int wm = w >> 2, wn = w & 3;
    const int l15 = lane & 15, l4 = lane >> 4, sx = lane & 7;

    int bid = blockIdx.x;
    int swz = (bid & 7) * 64 + (bid >> 3);
    int nblk = swz >> 6, mblk = swz & 63;
    const int mrow0 = mblk * 256;
    const int nrow0 = nblk * 256;

    const int abase = wm * 16384 + l15 * 128;
    const int bbase = 32768 + (wn >> 1) * 16384 + ((wn & 1) * 64 + l15) * 128;
    int kof[2];
#pragma unroll
    for (int kk = 0; kk < 2; kk++) kof[kk] = ((kk * 4 + l4) ^ sx) << 4;

    f32x4 acc[8][4];
#pragma unroll
    for (int m = 0; m < 8; m++)
#pragma unroll
        for (int n = 0; n < 4; n++) acc[m][n] = (f32x4){0.f, 0.f, 0.f, 0.f};
    short8 areg[4][2];
    short8 breg[4][2];

    STG(0, 0, 0, 0); STG(0, 0, 1, 0); STG(1, 0, 0, 0); STG(1, 0, 1, 0);
    STG(0, 1, 0, 1); STG(0, 1, 1, 1); STG(1, 1, 0, 1); STG(1, 1, 1, 1);
    asm volatile("s_waitcnt vmcnt(8)" ::: "memory");
    BARX();
    DSA(0, 0); DSB(0, 0); DSB(1, 0);

    for (int it2 = 0; it2 < 16; ++it2) {
#pragma unroll
        for (int c = 0; c < 2; ++c) {
            const int tt = 2 * it2 + c;
            WLG("4");  MMAQ(0, 0);
            WLG("0");  MMAQ(0, 1);
            DSA(1, c);
            WLG("0");  MMAQ(1, 0);
            asm volatile("s_waitcnt vmcnt(0)" ::: "memory");
            BARX();
            if (tt < 30) { STG(0, c, 0, tt + 2); STG(0, c, 1, tt + 2);
                           STG(1, c, 0, tt + 2); STG(1, c, 1, tt + 2); }
            MMAQ(1, 1);
            if (tt < 31) { DSA(0, c ^ 1); DSB(0, c ^ 1); DSB(1, c ^ 1); }
        }
    }

#pragma unroll
    for (int m = 0; m < 8; m++)
#pragma unroll
        for (int n = 0; n < 4; n++) {
            int col = nrow0 + wn * 64 + n * 16 + l15;
            float bias = b3[col];
            int row = mrow0 + wm * 128 + m * 16 + l4 * 4;
#pragma unroll
            for (int j = 0; j < 4; j++)
                __builtin_nontemporal_store(acc[m][n][j] + bias,
                                            &out[(size_t)(row + j) * 2048 + col]);
        }
}

// ---------------------------------------------------------------------------
extern "C" void kernel_launch(void* const* d_in, const int* in_sizes, int n_in,
                              void* d_out, int out_size, void* d_ws, size_t ws_size,
                              hipStream_t stream) {
    const float* x   = (const float*)d_in[0];
    const float* sw  = (const float*)d_in[1];
    const float* swb = (const float*)d_in[2];
    const float* w1  = (const float*)d_in[3];
    const float* b1  = (const float*)d_in[4];
    const float* w2  = (const float*)d_in[5];
    const float* b2  = (const float*)d_in[6];
    const float* w3  = (const float*)d_in[7];
    const float* b3  = (const float*)d_in[8];
    float* out = (float*)d_out;

    char* ws = (char*)d_ws;
    float* part = (float*)(ws + 0);                 // 128 KB
    float* gate = (float*)(ws + 131072);            // 64 B
    int*   idx  = (int*)(ws + 131136);              // 64 B
    float* bc   = (float*)(ws + 131200);            // 4 KB
    u16*   w1b  = (u16*)(ws + 262144);              // 256 KB (swizzled)
    u16*   w2b  = (u16*)(ws + 524288);              // 256 KB
    u16*   w3b  = (u16*)(ws + 786432);              // 8 MB
    u16*   y    = (u16*)(ws + 9175040);             // 64 MB
    u16*   xb   = (u16*)(ws + 76283904);            // 64 MB (swizzled bf16 x)
    const size_t need_xb = 143392768;
    const bool xbmode = ws_size >= need_xb;

    hipFuncSetAttribute((const void*)final_gemm256,
                        hipFuncAttributeMaxDynamicSharedMemorySize, 131072);

    if (xbmode)
        hipLaunchKernelGGL((router_partial<1>), dim3(NCHUNK), dim3(256), 0, stream, x, sw, part, xb);
    else
        hipLaunchKernelGGL((router_partial<0>), dim3(NCHUNK), dim3(256), 0, stream, x, sw, part, xb);
    hipLaunchKernelGGL(router_finish, dim3(1), dim3(128), 0, stream, part, swb, b2, gate, idx, bc);
    hipLaunchKernelGGL(convert_w12, dim3(256), dim3(256), 0, stream, w1, w2, w1b, w2b);
    hipLaunchKernelGGL(convert_w3, dim3(D_ * D_ / 1024), dim3(256), 0, stream, w3, w3b);
    if (xbmode)
        hipLaunchKernelGGL((mlp_kernel<1>), dim3(64, 8), dim3(512), 0, stream,
                           (const void*)xb, w1b, w2b, b1, gate, idx, bc, y);
    else
        hipLaunchKernelGGL((mlp_kernel<0>), dim3(64, 8), dim3(512), 0, stream,
                           (const void*)x, w1b, w2b, b1, gate, idx, bc, y);
    hipLaunchKernelGGL(final_gemm256, dim3(512), dim3(512), 131072, stream,
                       y, w3b, b3, out);
}

// Round 11
// 312.012 us; speedup vs baseline: 1.0731x; 1.0052x over previous
//
#include <hip/hip_runtime.h>
#include <math.h>

typedef unsigned short u16;
typedef unsigned int u32;
typedef __attribute__((ext_vector_type(8))) short short8;
typedef __attribute__((ext_vector_type(4))) float f32x4;
typedef __attribute__((ext_vector_type(4))) unsigned short ushort4v;

#define B_ 8
#define S_ 2048
#define D_ 2048
#define H_ 16
#define RLEN 4194304   // S_*D_ elems per batch sample
#define NCHUNK 512

static __device__ __forceinline__ u16 f2bf(float f) {
    union { float f; u32 u; } v; v.f = f;
    u32 r = v.u + 0x7fffu + ((v.u >> 16) & 1u);
    return (u16)(r >> 16);
}
static __device__ __forceinline__ float bf2f(u16 u) {
    union { u32 u; float f; } v; v.u = ((u32)u) << 16;
    return v.f;
}
// fast tanh-GELU (|err| <= ~3e-3 vs exact, within bf16 budget)
static __device__ __forceinline__ float gelu_fast(float v) {
    float z = 1.5957691216057308f * v * (1.0f + 0.044715f * v * v);
    float e = __expf(z);
    float r = __builtin_amdgcn_rcpf(e + 1.0f);
    return v * (1.0f - r);
}
// non-temporal float4 load via clang ext-vector (HIP_vector_type not accepted)
static __device__ __forceinline__ f32x4 ntload4(const float* p) {
    return __builtin_nontemporal_load((const f32x4*)p);
}

typedef const __attribute__((address_space(1))) u32* gas1_t;
typedef __attribute__((address_space(3))) u32* las3_t;
static __device__ __forceinline__ void gload_lds16(const void* g, void* l) {
    __builtin_amdgcn_global_load_lds((gas1_t)g, (las3_t)l, 16, 0, 0);
}

// ---------------- Kernel 1: router partial dots (+ fused x->bf16 swizzled) --
// nt-loads on x/sw: both are read-once streams; keep L3 clean for xb.
template<int XB>
__global__ __launch_bounds__(256, 3) void router_partial(const float* __restrict__ x,
                                                         const float* __restrict__ sw,
                                                         float* __restrict__ part,
                                                         u16* __restrict__ xb) {
    int c = blockIdx.x;
    int t = threadIdx.x;
    const int chunk = RLEN / NCHUNK;        // 8192
    int base = c * chunk;
    float acc[8][8];
#pragma unroll
    for (int b = 0; b < 8; b++)
#pragma unroll
        for (int e = 0; e < 8; e++) acc[b][e] = 0.f;

    for (int it = 0; it < chunk / (256 * 4); ++it) {   // 8 iterations
        int i = base + (it * 256 + t) * 4;
        f32x4 xv[8];
#pragma unroll
        for (int b = 0; b < 8; b++) xv[b] = ntload4(&x[(size_t)b * RLEN + i]);
        if (XB) {
            int row = i >> 7, col = i & 127;
            int scol = (((col >> 3) ^ (row & 7)) << 3) | (col & 7);
#pragma unroll
            for (int b = 0; b < 8; b++) {
                ushort4v u;
                u.x = f2bf(xv[b].x); u.y = f2bf(xv[b].y);
                u.z = f2bf(xv[b].z); u.w = f2bf(xv[b].w);
                *(ushort4v*)&xb[(size_t)b * RLEN + (size_t)row * 128 + scol] = u;
            }
        }
        f32x4 sv = ntload4(&sw[i]);
#pragma unroll
        for (int e = 0; e < 8; e++) {
            f32x4 svn;
            if (e < 7) svn = ntload4(&sw[(size_t)(e + 1) * RLEN + i]);
#pragma unroll
            for (int b = 0; b < 8; b++)
                acc[b][e] += xv[b].x * sv.x + xv[b].y * sv.y +
                             xv[b].z * sv.z + xv[b].w * sv.w;
            sv = svn;
        }
    }

    __shared__ float red[4][64];
    int lane = t & 63, wv = t >> 6;
#pragma unroll
    for (int q = 0; q < 64; q++) {
        float v = acc[q >> 3][q & 7];
#pragma unroll
        for (int m = 32; m >= 1; m >>= 1) v += __shfl_xor(v, m, 64);
        if (lane == 0) red[wv][q] = v;
    }
    __syncthreads();
    if (t < 64) {
        float s = red[0][t] + red[1][t] + red[2][t] + red[3][t];
        part[(size_t)t * NCHUNK + c] = s;
    }
}

// ---------------- Kernel 2: reduce + softmax + top-2 + combined b2 bias ----
__global__ __launch_bounds__(128) void router_finish(const float* __restrict__ part,
                                                     const float* __restrict__ swb,
                                                     const float* __restrict__ b2,
                                                     float* __restrict__ gate,
                                                     int* __restrict__ idx,
                                                     float* __restrict__ bc) {
    int t = threadIdx.x;
    __shared__ float lg[64];
    __shared__ float sg[16];
    __shared__ int   si[16];
    if (t < 64) {
        float s = 0.f;
        for (int c = 0; c < NCHUNK; c++) s += part[(size_t)t * NCHUNK + c];
        lg[t] = s + swb[t & 7];
    }
    __syncthreads();
    if (t < 8) {
        int b = t;
        float m = -1e30f;
        for (int e = 0; e < 8; e++) m = fmaxf(m, lg[b * 8 + e]);
        float p[8]; float sum = 0.f;
        for (int e = 0; e < 8; e++) { p[e] = expf(lg[b * 8 + e] - m); sum += p[e]; }
        for (int e = 0; e < 8; e++) p[e] /= sum;
        int i1 = 0; float v1 = p[0];
        for (int e = 1; e < 8; e++) if (p[e] > v1) { v1 = p[e]; i1 = e; }
        int i2 = -1; float v2 = -1.f;
        for (int e = 0; e < 8; e++) if (e != i1 && p[e] > v2) { v2 = p[e]; i2 = e; }
        gate[b * 2 + 0] = v1; gate[b * 2 + 1] = v2;
        idx[b * 2 + 0] = i1;  idx[b * 2 + 1] = i2;
        sg[b * 2] = v1; sg[b * 2 + 1] = v2;
        si[b * 2] = i1; si[b * 2 + 1] = i2;
    }
    __syncthreads();
    for (int b = 0; b < 8; b++)
        bc[b * 128 + t] = sg[b * 2] * b2[si[b * 2] * 128 + t] +
                          sg[b * 2 + 1] * b2[si[b * 2 + 1] * 128 + t];
}

// ---------------- Kernel 3a: w1/w2 -> bf16 (w1 swizzled) -------------------
__global__ __launch_bounds__(256) void convert_w12(const float* __restrict__ w1,
                                                   const float* __restrict__ w2,
                                                   u16* __restrict__ w1b,
                                                   u16* __restrict__ w2b) {
    int i4 = (blockIdx.x * 256 + threadIdx.x) * 4;
    if (i4 < 131072) {
        int k = i4 & 127, f = (i4 >> 7) & 127;
        float4 v = *(const float4*)&w1[i4];
        int sc = ((((k >> 3) ^ (f & 7)) << 3) | (k & 7));
        ushort4v u;
        u.x = f2bf(v.x); u.y = f2bf(v.y); u.z = f2bf(v.z); u.w = f2bf(v.w);
        *(ushort4v*)&w1b[(i4 & ~127) + sc] = u;
    } else {
        int j = i4 - 131072;
        float4 v = *(const float4*)&w2[j];
        ushort4v u;
        u.x = f2bf(v.x); u.y = f2bf(v.y); u.z = f2bf(v.z); u.w = f2bf(v.w);
        *(ushort4v*)&w2b[j] = u;
    }
}

// ---------------- Kernel 3b: w3 -> bf16 ------------------------------------
__global__ __launch_bounds__(256) void convert_w3(const float* __restrict__ w3,
                                                  u16* __restrict__ w3b) {
    size_t i = ((size_t)blockIdx.x * 256 + threadIdx.x) * 4;
    float4 v = *(const float4*)&w3[i];
    u16* d = &w3b[i];
    d[0] = f2bf(v.x); d[1] = f2bf(v.y); d[2] = f2bf(v.z); d[3] = f2bf(v.w);
}

// ---------------- Kernel 4: expert MLP v4 — vectorized stores via ob -------
template<int XB>
__global__ __launch_bounds__(512) void mlp_kernel(const void* __restrict__ xsrc_,
                                                  const u16* __restrict__ w1b,
                                                  const u16* __restrict__ w2b,
                                                  const float* __restrict__ b1,
                                                  const float* __restrict__ gate,
                                                  const int* __restrict__ idx,
                                                  const float* __restrict__ bc,
                                                  u16* __restrict__ y) {
    __shared__ __align__(16) u16 w1s[256 * 128];   // 64 KB (both experts)
    __shared__ __align__(16) u16 xs[2][64 * 128];  // 32 KB
    __shared__ __align__(16) u16 hb[2][32 * 256];  // 32 KB
    __shared__ __align__(16) u16 ob[2][32 * 128];  // 16 KB  (144 KB total)
    const int t = threadIdx.x, lane = t & 63, w = t >> 6;
    const int wr = w >> 2, wq = w & 3;
    const int l15 = lane & 15, l4 = lane >> 4;
    const int b = blockIdx.y, grp = blockIdx.x;
    const size_t xbase = (size_t)b * RLEN;
    const size_t gbase = xbase + (size_t)grp * 65536;
    const int e0 = idx[b * 2], e1 = idx[b * 2 + 1];
    const int slot = wq >> 1;
    const float gw = gate[b * 2 + slot];
    const float* b1p = b1 + (slot ? e1 : e0) * 128;

    float b1v[4];
#pragma unroll
    for (int nt = 0; nt < 4; nt++) b1v[nt] = b1p[(wq & 1) * 64 + nt * 16 + l15];
    float bcv[2];
#pragma unroll
    for (int n = 0; n < 2; n++) bcv[n] = bc[b * 128 + wq * 32 + n * 16 + l15];

    short8 w2f[2][8];
#pragma unroll
    for (int n = 0; n < 2; n++) {
        int d = wq * 32 + n * 16 + l15;
#pragma unroll
        for (int kb = 0; kb < 8; kb++) {
            int e = (kb >= 4) ? e1 : e0;
            int f = (kb & 3) * 32 + l4 * 8;
            w2f[n][kb] = *(const short8*)&w2b[((size_t)(e * 128 + d)) * 128 + f];
        }
    }

#pragma unroll
    for (int p = 0; p < 8; p++) {
        int elem = p * 4096 + t * 8;
        int frow = elem >> 7, col = elem & 127;
        int e = (frow >= 128) ? e1 : e0;
        gload_lds16(w1b + ((size_t)(e * 128 + (frow & 127))) * 128 + col,
                    (char*)w1s + elem * 2);
    }
    if (XB) {
        const u16* xbp = (const u16*)xsrc_;
#pragma unroll
        for (int T = 0; T < 2; T++) {
            gload_lds16(xbp + gbase + T * 8192 + t * 8, (char*)&xs[T][0] + t * 16);
            gload_lds16(xbp + gbase + T * 8192 + 4096 + t * 8,
                        (char*)&xs[T][0] + 8192 + t * 16);
        }
        asm volatile("s_waitcnt vmcnt(0)" ::: "memory");
    } else {
        const float* xf = (const float*)xsrc_;
#pragma unroll
        for (int T = 0; T < 2; T++)
#pragma unroll
            for (int p = 0; p < 4; p++) {
                int elem = p * 2048 + t * 4;
                int row = elem >> 7, col = elem & 127;
                float4 v = *(const float4*)&xf[gbase + T * 8192 + elem];
                ushort4v u;
                u.x = f2bf(v.x); u.y = f2bf(v.y); u.z = f2bf(v.z); u.w = f2bf(v.w);
                *(ushort4v*)((char*)&xs[T][0] + row * 256 +
                             (((col >> 3) ^ (row & 7)) << 4) + (col & 7) * 2) = u;
            }
        asm volatile("s_waitcnt vmcnt(0) lgkmcnt(0)" ::: "memory");
    }
    __builtin_amdgcn_s_barrier();

    auto G1 = [&](int st, f32x4* a1) {
        const u16* xc = &xs[(st >> 1) & 1][0];
        int rbase = (st & 1) * 32 + wr * 16 + l15;
#pragma unroll
        for (int nt = 0; nt < 4; nt++) a1[nt] = (f32x4){0.f, 0.f, 0.f, 0.f};
#pragma unroll
        for (int kb = 0; kb < 4; kb++) {
            int kg = kb * 4 + l4;
            short8 a = *(const short8*)&xc[rbase * 128 + ((kg ^ (rbase & 7)) << 3)];
#pragma unroll
            for (int nt = 0; nt < 4; nt++) {
                int fr = wq * 64 + nt * 16 + l15;
                short8 bb = *(const short8*)&w1s[fr * 128 + ((kg ^ (fr & 7)) << 3)];
                a1[nt] = __builtin_amdgcn_mfma_f32_16x16x32_bf16(a, bb, a1[nt], 0, 0, 0);
            }
        }
    };
    auto GELU_ST = [&](int st, f32x4* a1) {
        u16* hd = &hb[st & 1][0];
#pragma unroll
        for (int nt = 0; nt < 4; nt++) {
            int fcol = wq * 64 + nt * 16 + l15;
#pragma unroll
            for (int j = 0; j < 4; j++) {
                int row = wr * 16 + l4 * 4 + j;
                float v = a1[nt][j] + b1v[nt];
                v = gelu_fast(v) * gw;
                hd[row * 256 + ((((fcol >> 3) ^ (row & 7)) << 3) | (fcol & 7))] = f2bf(v);
            }
        }
    };
    auto G2 = [&](int st, f32x4* a2) {
        const u16* hs = &hb[st & 1][0];
        int arow = wr * 16 + l15;
        a2[0] = (f32x4){0.f, 0.f, 0.f, 0.f};
        a2[1] = (f32x4){0.f, 0.f, 0.f, 0.f};
#pragma unroll
        for (int kb = 0; kb < 8; kb++) {
            int fg = kb * 4 + l4;
            short8 a = *(const short8*)&hs[arow * 256 + ((fg ^ (arow & 7)) << 3)];
            a2[0] = __builtin_amdgcn_mfma_f32_16x16x32_bf16(a, w2f[0][kb], a2[0], 0, 0, 0);
            a2[1] = __builtin_amdgcn_mfma_f32_16x16x32_bf16(a, w2f[1][kb], a2[1], 0, 0, 0);
        }
    };
    auto OWRITE = [&](int st, f32x4* a2) {
        u16* od = &ob[st & 1][0];
        const u16* xc = &xs[(st >> 1) & 1][0];
#pragma unroll
        for (int n = 0; n < 2; n++) {
            int d = wq * 32 + n * 16 + l15;
#pragma unroll
            for (int j = 0; j < 4; j++) {
                int row = wr * 16 + l4 * 4 + j;
                int xrow = (st & 1) * 32 + row;
                float xr = bf2f(xc[xrow * 128 + ((((d >> 3) ^ (xrow & 7)) << 3) | (d & 7))]);
                od[row * 128 + (d ^ ((row & 7) << 3))] = f2bf(a2[n][j] + bcv[n] + xr);
            }
        }
    };
    auto YSTV = [&](int st) {
        int row = t >> 4;
        int cg = t & 15;
        const u16* os = &ob[st & 1][0];
        short8 v = *(const short8*)&os[row * 128 + ((cg ^ (row & 7)) << 3)];
        u16* yb = y + xbase + (size_t)grp * 65536 + st * 4096;
        *(short8*)&yb[row * 128 + cg * 8] = v;
    };

    {
        f32x4 a1[4];
        G1(0, a1);
        GELU_ST(0, a1);
    }
    asm volatile("s_waitcnt lgkmcnt(0)" ::: "memory");
    __builtin_amdgcn_s_barrier();

    for (int st = 0; st < 17; ++st) {
        const bool stg = (st < 16) && ((st & 1) == 0) && st >= 2 && st <= 12;
        if (st < 16) {
            f32x4 a1n[4];
            if (st < 15) G1(st + 1, a1n);
            f32x4 a2[2];
            G2(st, a2);
            if (st < 15) GELU_ST(st + 1, a1n);
            OWRITE(st, a2);
        }
        if (stg) {
            int T = st / 2 + 1;
            if (XB) {
                const u16* xbp = (const u16*)xsrc_;
                gload_lds16(xbp + gbase + T * 8192 + t * 8, (char*)&xs[T & 1][0] + t * 16);
                gload_lds16(xbp + gbase + T * 8192 + 4096 + t * 8,
                            (char*)&xs[T & 1][0] + 8192 + t * 16);
            } else {
                const float* xf = (const float*)xsrc_;
#pragma unroll
                for (int p = 0; p < 4; p++) {
                    int elem = p * 2048 + t * 4;
                    int row = elem >> 7, col = elem & 127;
                    float4 v = *(const float4*)&xf[gbase + T * 8192 + elem];
                    ushort4v u;
                    u.x = f2bf(v.x); u.y = f2bf(v.y); u.z = f2bf(v.z); u.w = f2bf(v.w);
                    *(ushort4v*)((char*)&xs[T & 1][0] + row * 256 +
                                 (((col >> 3) ^ (row & 7)) << 4) + (col & 7) * 2) = u;
                }
            }
        }
        if (st >= 1) YSTV(st - 1);
        asm volatile("s_waitcnt lgkmcnt(0)" ::: "memory");
        if (stg && XB) asm volatile("s_waitcnt vmcnt(1)" ::: "memory");
        if (st < 16) __builtin_amdgcn_s_barrier();
    }
}

// ---------------- Kernel 5: out = y @ w3^T + b3, 256^2 m201 8-phase --------
// T_even -> buf0, T_odd -> buf1. Per iter (2 K-tiles), 8 phases, each:
// {ds-reads (12/4/8/0) || stage 1 half-tile (2 loads) -> bar -> lgkm0 ->
//  setprio(1) 16 MFMA setprio(0) -> bar}. Counted vmcnt(4) ONLY at P4/P8.
// Stage slots (region-lifetime-derived; waves read A-half wm at P1&P3,
// B-half wn>>1 at P1&P2):  P1/P2: T_odd A-halves -> buf1 (read this iter
// P5/P7, landed by P4 vmcnt);  P3/P4: T_even+2 B -> buf0;  P5/P6: T_even+2
// A -> buf0 (all landed by P8 vmcnt, read next P1-P3);  P7/P8: T_odd+2 B
// -> buf1 (landed by next P4 vmcnt, read next P5/P6). All WAR gaps >= 1
// barrier after last ds_read retire.
#define BARX() do { asm volatile("" ::: "memory"); __builtin_amdgcn_s_barrier(); \
                    asm volatile("" ::: "memory"); } while (0)
#define WLGC(NSTR) do { asm volatile("s_waitcnt lgkmcnt(" NSTR ")" ::: "memory"); \
                        __builtin_amdgcn_sched_barrier(0); } while (0)
#define WVMC(NSTR) do { asm volatile("s_waitcnt vmcnt(" NSTR ")" ::: "memory"); \
                        __builtin_amdgcn_sched_barrier(0); } while (0)

#define DSA(mh, c) do { \
    const char* _ba = smem + (c) * 65536 + abase; \
    _Pragma("unroll") for (int mf = 0; mf < 4; mf++) \
    _Pragma("unroll") for (int kk = 0; kk < 2; kk++) \
        areg[mf][kk] = *(const short8*)(_ba + ((mh) * 4 + mf) * 2048 + kof[kk]); \
} while (0)

#define DSB(nh, c) do { \
    const char* _bb = smem + (c) * 65536 + bbase; \
    _Pragma("unroll") for (int nf = 0; nf < 2; nf++) \
    _Pragma("unroll") for (int kk = 0; kk < 2; kk++) \
        breg[(nh) * 2 + nf][kk] = *(const short8*)(_bb + ((nh) * 2 + nf) * 2048 + kof[kk]); \
} while (0)

#define MMAQ(mh, nh) do { \
    __builtin_amdgcn_s_setprio(1); \
    _Pragma("unroll") for (int mf = 0; mf < 4; mf++) \
    _Pragma("unroll") for (int nf = 0; nf < 2; nf++) \
    _Pragma("unroll") for (int kk = 0; kk < 2; kk++) \
        acc[(mh) * 4 + mf][(nh) * 2 + nf] = __builtin_amdgcn_mfma_f32_16x16x32_bf16( \
            areg[mf][kk], breg[(nh) * 2 + nf][kk], acc[(mh) * 4 + mf][(nh) * 2 + nf], 0, 0, 0); \
    __builtin_amdgcn_s_setprio(0); \
} while (0)

#define STG(op, c, h, kt) do { \
    const u16* _gs = (op) ? wbp : yap; \
    int _tr0 = (op) ? nrow0 : mrow0; \
    _Pragma("unroll") for (int p = 0; p < 2; p++) { \
        int _idx = p * 512 + t; \
        int _row = _idx >> 3; \
        int _gcol = (((_idx & 7) ^ (_row & 7)) << 3); \
        gload_lds16(_gs + (size_t)(_tr0 + (h) * 128 + _row) * 2048 + (kt) * 64 + _gcol, \
                    smem + (c) * 65536 + (op) * 32768 + (h) * 16384 + _idx * 16); \
    } \
} while (0)

__global__ __launch_bounds__(512, 2) void final_gemm256(const u16* __restrict__ yap,
                                                        const u16* __restrict__ wbp,
                                                        const float* __restrict__ b3,
                                                        float* __restrict__ out) {
    extern __shared__ char smem[];
    const int t = threadIdx.x;
    const int lane = t & 63, w = t >> 6;
    const int wm = w >> 2, wn = w & 3;
    const int l15 = lane & 15, l4 = lane >> 4, sx = lane & 7;

    int bid = blockIdx.x;
    int swz = (bid & 7) * 64 + (bid >> 3);
    int nblk = swz >> 6, mblk = swz & 63;
    const int mrow0 = mblk * 256;
    const int nrow0 = nblk * 256;

    const int abase = wm * 16384 + l15 * 128;
    const int bbase = 32768 + (wn >> 1) * 16384 + ((wn & 1) * 64 + l15) * 128;
    int kof[2];
#pragma unroll
    for (int kk = 0; kk < 2; kk++) kof[kk] = ((kk * 4 + l4) ^ sx) << 4;

    f32x4 acc[8][4];
#pragma unroll
    for (int m = 0; m < 8; m++)
#pragma unroll
        for (int n = 0; n < 4; n++) acc[m][n] = (f32x4){0.f, 0.f, 0.f, 0.f};
    short8 areg[4][2];
    short8 breg[4][2];

    // prologue: T0{Bh0,Bh1,Ah0,Ah1} -> buf0, T1{Bh0,Bh1} -> buf1
    STG(1, 0, 0, 0); STG(1, 0, 1, 0); STG(0, 0, 0, 0); STG(0, 0, 1, 0);
    STG(1, 1, 0, 1); STG(1, 1, 1, 1);
    WVMC("4");      // T0 fully landed (leaves T1-B in flight)
    BARX();

    for (int i = 0; i < 15; ++i) {
        const int to = 2 * i + 1, te2 = 2 * i + 2, to2 = 2 * i + 3;
        // P1: Q00(buf0); stage T_odd-Ah0 -> buf1
        DSA(0, 0); DSB(0, 0); STG(0, 1, 0, to);
        WLGC("8"); BARX(); WLGC("0"); MMAQ(0, 0); BARX();
        // P2: Q01; stage T_odd-Ah1 -> buf1
        DSB(1, 0); STG(0, 1, 1, to);
        BARX(); WLGC("0"); MMAQ(0, 1); BARX();
        // P3: Q10; stage T_even+2-Bh0 -> buf0
        DSA(1, 0); STG(1, 0, 0, te2);
        BARX(); WLGC("0"); MMAQ(1, 0); BARX();
        // P4: Q11; stage T_even+2-Bh1 -> buf0; counted vmcnt
        STG(1, 0, 1, te2);
        WVMC("4"); BARX(); MMAQ(1, 1); BARX();
        // P5: Q00(buf1); stage T_even+2-Ah0 -> buf0
        DSA(0, 1); DSB(0, 1); STG(0, 0, 0, te2);
        WLGC("8"); BARX(); WLGC("0"); MMAQ(0, 0); BARX();
        // P6: Q01; stage T_even+2-Ah1 -> buf0
        DSB(1, 1); STG(0, 0, 1, te2);
        BARX(); WLGC("0"); MMAQ(0, 1); BARX();
        // P7: Q10; stage T_odd+2-Bh0 -> buf1
        DSA(1, 1); STG(1, 1, 0, to2);
        BARX(); WLGC("0"); MMAQ(1, 0); BARX();
        // P8: Q11; stage T_odd+2-Bh1 -> buf1; counted vmcnt
        STG(1, 1, 1, to2);
        WVMC("4"); BARX(); MMAQ(1, 1); BARX();
    }
    { // peel i=15: T30 in buf0, T31 in buf1; stage only T31-A at P1/P2
        DSA(0, 0); DSB(0, 0); STG(0, 1, 0, 31);
        WLGC("8"); BARX(); WLGC("0"); MMAQ(0, 0); BARX();
        DSB(1, 0); STG(0, 1, 1, 31);
        BARX(); WLGC("0"); MMAQ(0, 1); BARX();
        DSA(1, 0);
        BARX(); WLGC("0"); MMAQ(1, 0); BARX();
        WVMC("0"); BARX(); MMAQ(1, 1); BARX();   // full drain: T31 complete
        DSA(0, 1); DSB(0, 1);
        WLGC("8"); BARX(); WLGC("0"); MMAQ(0, 0); BARX();
        DSB(1, 1);
        BARX(); WLGC("0"); MMAQ(0, 1); BARX();
        DSA(1, 1);
        BARX(); WLGC("0"); MMAQ(1, 0); BARX();
        MMAQ(1, 1);
    }

    // epilogue: bias + fp32 store (plain stores; nt-store regressed in R10)
#pragma unroll
    for (int m = 0; m < 8; m++)
#pragma unroll
        for (int n = 0; n < 4; n++) {
            int col = nrow0 + wn * 64 + n * 16 + l15;
            float bias = b3[col];
            int row = mrow0 + wm * 128 + m * 16 + l4 * 4;
#pragma unroll
            for (int j = 0; j < 4; j++)
                out[(size_t)(row + j) * 2048 + col] = acc[m][n][j] + bias;
        }
}

// ---------------------------------------------------------------------------
extern "C" void kernel_launch(void* const* d_in, const int* in_sizes, int n_in,
                              void* d_out, int out_size, void* d_ws, size_t ws_size,
                              hipStream_t stream) {
    const float* x   = (const float*)d_in[0];
    const float* sw  = (const float*)d_in[1];
    const float* swb = (const float*)d_in[2];
    const float* w1  = (const float*)d_in[3];
    const float* b1  = (const float*)d_in[4];
    const float* w2  = (const float*)d_in[5];
    const float* b2  = (const float*)d_in[6];
    const float* w3  = (const float*)d_in[7];
    const float* b3  = (const float*)d_in[8];
    float* out = (float*)d_out;

    char* ws = (char*)d_ws;
    float* part = (float*)(ws + 0);                 // 128 KB
    float* gate = (float*)(ws + 131072);            // 64 B
    int*   idx  = (int*)(ws + 131136);              // 64 B
    float* bc   = (float*)(ws + 131200);            // 4 KB
    u16*   w1b  = (u16*)(ws + 262144);              // 256 KB (swizzled)
    u16*   w2b  = (u16*)(ws + 524288);              // 256 KB
    u16*   w3b  = (u16*)(ws + 786432);              // 8 MB
    u16*   y    = (u16*)(ws + 9175040);             // 64 MB
    u16*   xb   = (u16*)(ws + 76283904);            // 64 MB (swizzled bf16 x)
    const size_t need_xb = 143392768;
    const bool xbmode = ws_size >= need_xb;

    hipFuncSetAttribute((const void*)final_gemm256,
                        hipFuncAttributeMaxDynamicSharedMemorySize, 131072);

    if (xbmode)
        hipLaunchKernelGGL((router_partial<1>), dim3(NCHUNK), dim3(256), 0, stream, x, sw, part, xb);
    else
        hipLaunchKernelGGL((router_partial<0>), dim3(NCHUNK), dim3(256), 0, stream, x, sw, part, xb);
    hipLaunchKernelGGL(router_finish, dim3(1), dim3(128), 0, stream, part, swb, b2, gate, idx, bc);
    hipLaunchKernelGGL(convert_w12, dim3(256), dim3(256), 0, stream, w1, w2, w1b, w2b);
    hipLaunchKernelGGL(convert_w3, dim3(D_ * D_ / 1024), dim3(256), 0, stream, w3, w3b);
    if (xbmode)
        hipLaunchKernelGGL((mlp_kernel<1>), dim3(64, 8), dim3(512), 0, stream,
                           (const void*)xb, w1b, w2b, b1, gate, idx, bc, y);
    else
        hipLaunchKernelGGL((mlp_kernel<0>), dim3(64, 8), dim3(512), 0, stream,
                           (const void*)x, w1b, w2b, b1, gate, idx, bc, y);
    hipLaunchKernelGGL(final_gemm256, dim3(512), dim3(512), 131072, stream,
                       y, w3b, b3, out);
}

// Round 12
// 295.622 us; speedup vs baseline: 1.1326x; 1.0554x over previous
//
#include <hip/hip_runtime.h>
#include <math.h>

typedef unsigned short u16;
typedef unsigned int u32;
typedef __attribute__((ext_vector_type(8))) short short8;
typedef __attribute__((ext_vector_type(4))) float f32x4;
typedef __attribute__((ext_vector_type(4))) unsigned short ushort4v;

#define B_ 8
#define S_ 2048
#define D_ 2048
#define H_ 16
#define RLEN 4194304   // S_*D_ elems per batch sample
#define NCHUNK 512

static __device__ __forceinline__ u16 f2bf(float f) {
    union { float f; u32 u; } v; v.f = f;
    u32 r = v.u + 0x7fffu + ((v.u >> 16) & 1u);
    return (u16)(r >> 16);
}
static __device__ __forceinline__ float bf2f(u16 u) {
    union { u32 u; float f; } v; v.u = ((u32)u) << 16;
    return v.f;
}
// fast tanh-GELU (|err| <= ~3e-3 vs exact, within bf16 budget)
static __device__ __forceinline__ float gelu_fast(float v) {
    float z = 1.5957691216057308f * v * (1.0f + 0.044715f * v * v);
    float e = __expf(z);
    float r = __builtin_amdgcn_rcpf(e + 1.0f);
    return v * (1.0f - r);
}
// non-temporal float4 load via clang ext-vector (HIP_vector_type not accepted)
static __device__ __forceinline__ f32x4 ntload4(const float* p) {
    return __builtin_nontemporal_load((const f32x4*)p);
}

typedef const __attribute__((address_space(1))) u32* gas1_t;
typedef __attribute__((address_space(3))) u32* las3_t;
static __device__ __forceinline__ void gload_lds16(const void* g, void* l) {
    __builtin_amdgcn_global_load_lds((gas1_t)g, (las3_t)l, 16, 0, 0);
}

// ---------------- Kernel 1: router partial dots (+ fused x->bf16 swizzled) --
// nt-loads on x/sw: both are read-once streams; keep L3 clean for xb.
template<int XB>
__global__ __launch_bounds__(256, 3) void router_partial(const float* __restrict__ x,
                                                         const float* __restrict__ sw,
                                                         float* __restrict__ part,
                                                         u16* __restrict__ xb) {
    int c = blockIdx.x;
    int t = threadIdx.x;
    const int chunk = RLEN / NCHUNK;        // 8192
    int base = c * chunk;
    float acc[8][8];
#pragma unroll
    for (int b = 0; b < 8; b++)
#pragma unroll
        for (int e = 0; e < 8; e++) acc[b][e] = 0.f;

    for (int it = 0; it < chunk / (256 * 4); ++it) {   // 8 iterations
        int i = base + (it * 256 + t) * 4;
        f32x4 xv[8];
#pragma unroll
        for (int b = 0; b < 8; b++) xv[b] = ntload4(&x[(size_t)b * RLEN + i]);
        if (XB) {
            int row = i >> 7, col = i & 127;
            int scol = (((col >> 3) ^ (row & 7)) << 3) | (col & 7);
#pragma unroll
            for (int b = 0; b < 8; b++) {
                ushort4v u;
                u.x = f2bf(xv[b].x); u.y = f2bf(xv[b].y);
                u.z = f2bf(xv[b].z); u.w = f2bf(xv[b].w);
                *(ushort4v*)&xb[(size_t)b * RLEN + (size_t)row * 128 + scol] = u;
            }
        }
        f32x4 sv = ntload4(&sw[i]);
#pragma unroll
        for (int e = 0; e < 8; e++) {
            f32x4 svn;
            if (e < 7) svn = ntload4(&sw[(size_t)(e + 1) * RLEN + i]);
#pragma unroll
            for (int b = 0; b < 8; b++)
                acc[b][e] += xv[b].x * sv.x + xv[b].y * sv.y +
                             xv[b].z * sv.z + xv[b].w * sv.w;
            sv = svn;
        }
    }

    __shared__ float red[4][64];
    int lane = t & 63, wv = t >> 6;
#pragma unroll
    for (int q = 0; q < 64; q++) {
        float v = acc[q >> 3][q & 7];
#pragma unroll
        for (int m = 32; m >= 1; m >>= 1) v += __shfl_xor(v, m, 64);
        if (lane == 0) red[wv][q] = v;
    }
    __syncthreads();
    if (t < 64) {
        float s = red[0][t] + red[1][t] + red[2][t] + red[3][t];
        part[(size_t)t * NCHUNK + c] = s;
    }
}

// ---------------- Kernel 2: reduce + softmax + top-2 + combined b2 bias ----
// Parallelized part-sum: 512 threads (8 per (b,e) row) + shuffle tree.
__global__ __launch_bounds__(512) void router_finish(const float* __restrict__ part,
                                                     const float* __restrict__ swb,
                                                     const float* __restrict__ b2,
                                                     float* __restrict__ gate,
                                                     int* __restrict__ idx,
                                                     float* __restrict__ bc) {
    int t = threadIdx.x;
    __shared__ float lg[64];
    __shared__ float sg[16];
    __shared__ int   si[16];
    {
        int row = t >> 3, seg = t & 7;
        const float* p = part + (size_t)row * NCHUNK + seg * 64;
        float s = 0.f;
#pragma unroll 8
        for (int c = 0; c < 64; c++) s += p[c];
#pragma unroll
        for (int m = 4; m >= 1; m >>= 1) s += __shfl_down(s, m, 64);
        if (seg == 0) lg[row] = s + swb[row & 7];
    }
    __syncthreads();
    if (t < 8) {
        int b = t;
        float m = -1e30f;
        for (int e = 0; e < 8; e++) m = fmaxf(m, lg[b * 8 + e]);
        float p[8]; float sum = 0.f;
        for (int e = 0; e < 8; e++) { p[e] = expf(lg[b * 8 + e] - m); sum += p[e]; }
        for (int e = 0; e < 8; e++) p[e] /= sum;
        int i1 = 0; float v1 = p[0];
        for (int e = 1; e < 8; e++) if (p[e] > v1) { v1 = p[e]; i1 = e; }
        int i2 = -1; float v2 = -1.f;
        for (int e = 0; e < 8; e++) if (e != i1 && p[e] > v2) { v2 = p[e]; i2 = e; }
        gate[b * 2 + 0] = v1; gate[b * 2 + 1] = v2;
        idx[b * 2 + 0] = i1;  idx[b * 2 + 1] = i2;
        sg[b * 2] = v1; sg[b * 2 + 1] = v2;
        si[b * 2] = i1; si[b * 2 + 1] = i2;
    }
    __syncthreads();
    if (t < 128)
        for (int b = 0; b < 8; b++)
            bc[b * 128 + t] = sg[b * 2] * b2[si[b * 2] * 128 + t] +
                              sg[b * 2 + 1] * b2[si[b * 2 + 1] * 128 + t];
}

// ---------------- Kernel 3a: w1/w2 -> bf16 (w1 swizzled) -------------------
__global__ __launch_bounds__(256) void convert_w12(const float* __restrict__ w1,
                                                   const float* __restrict__ w2,
                                                   u16* __restrict__ w1b,
                                                   u16* __restrict__ w2b) {
    int i4 = (blockIdx.x * 256 + threadIdx.x) * 4;
    if (i4 < 131072) {
        int k = i4 & 127, f = (i4 >> 7) & 127;
        float4 v = *(const float4*)&w1[i4];
        int sc = ((((k >> 3) ^ (f & 7)) << 3) | (k & 7));
        ushort4v u;
        u.x = f2bf(v.x); u.y = f2bf(v.y); u.z = f2bf(v.z); u.w = f2bf(v.w);
        *(ushort4v*)&w1b[(i4 & ~127) + sc] = u;
    } else {
        int j = i4 - 131072;
        float4 v = *(const float4*)&w2[j];
        ushort4v u;
        u.x = f2bf(v.x); u.y = f2bf(v.y); u.z = f2bf(v.z); u.w = f2bf(v.w);
        *(ushort4v*)&w2b[j] = u;
    }
}

// ---------------- Kernel 3b: w3 -> bf16 ------------------------------------
__global__ __launch_bounds__(256) void convert_w3(const float* __restrict__ w3,
                                                  u16* __restrict__ w3b) {
    size_t i = ((size_t)blockIdx.x * 256 + threadIdx.x) * 4;
    float4 v = *(const float4*)&w3[i];
    u16* d = &w3b[i];
    d[0] = f2bf(v.x); d[1] = f2bf(v.y); d[2] = f2bf(v.z); d[3] = f2bf(v.w);
}

// ---------------- Kernel 4: expert MLP v4 — vectorized stores via ob -------
template<int XB>
__global__ __launch_bounds__(512) void mlp_kernel(const void* __restrict__ xsrc_,
                                                  const u16* __restrict__ w1b,
                                                  const u16* __restrict__ w2b,
                                                  const float* __restrict__ b1,
                                                  const float* __restrict__ gate,
                                                  const int* __restrict__ idx,
                                                  const float* __restrict__ bc,
                                                  u16* __restrict__ y) {
    __shared__ __align__(16) u16 w1s[256 * 128];   // 64 KB (both experts)
    __shared__ __align__(16) u16 xs[2][64 * 128];  // 32 KB
    __shared__ __align__(16) u16 hb[2][32 * 256];  // 32 KB
    __shared__ __align__(16) u16 ob[2][32 * 128];  // 16 KB  (144 KB total)
    const int t = threadIdx.x, lane = t & 63, w = t >> 6;
    const int wr = w >> 2, wq = w & 3;
    const int l15 = lane & 15, l4 = lane >> 4;
    const int b = blockIdx.y, grp = blockIdx.x;
    const size_t xbase = (size_t)b * RLEN;
    const size_t gbase = xbase + (size_t)grp * 65536;
    const int e0 = idx[b * 2], e1 = idx[b * 2 + 1];
    const int slot = wq >> 1;
    const float gw = gate[b * 2 + slot];
    const float* b1p = b1 + (slot ? e1 : e0) * 128;

    float b1v[4];
#pragma unroll
    for (int nt = 0; nt < 4; nt++) b1v[nt] = b1p[(wq & 1) * 64 + nt * 16 + l15];
    float bcv[2];
#pragma unroll
    for (int n = 0; n < 2; n++) bcv[n] = bc[b * 128 + wq * 32 + n * 16 + l15];

    short8 w2f[2][8];
#pragma unroll
    for (int n = 0; n < 2; n++) {
        int d = wq * 32 + n * 16 + l15;
#pragma unroll
        for (int kb = 0; kb < 8; kb++) {
            int e = (kb >= 4) ? e1 : e0;
            int f = (kb & 3) * 32 + l4 * 8;
            w2f[n][kb] = *(const short8*)&w2b[((size_t)(e * 128 + d)) * 128 + f];
        }
    }

#pragma unroll
    for (int p = 0; p < 8; p++) {
        int elem = p * 4096 + t * 8;
        int frow = elem >> 7, col = elem & 127;
        int e = (frow >= 128) ? e1 : e0;
        gload_lds16(w1b + ((size_t)(e * 128 + (frow & 127))) * 128 + col,
                    (char*)w1s + elem * 2);
    }
    if (XB) {
        const u16* xbp = (const u16*)xsrc_;
#pragma unroll
        for (int T = 0; T < 2; T++) {
            gload_lds16(xbp + gbase + T * 8192 + t * 8, (char*)&xs[T][0] + t * 16);
            gload_lds16(xbp + gbase + T * 8192 + 4096 + t * 8,
                        (char*)&xs[T][0] + 8192 + t * 16);
        }
        asm volatile("s_waitcnt vmcnt(0)" ::: "memory");
    } else {
        const float* xf = (const float*)xsrc_;
#pragma unroll
        for (int T = 0; T < 2; T++)
#pragma unroll
            for (int p = 0; p < 4; p++) {
                int elem = p * 2048 + t * 4;
                int row = elem >> 7, col = elem & 127;
                float4 v = *(const float4*)&xf[gbase + T * 8192 + elem];
                ushort4v u;
                u.x = f2bf(v.x); u.y = f2bf(v.y); u.z = f2bf(v.z); u.w = f2bf(v.w);
                *(ushort4v*)((char*)&xs[T][0] + row * 256 +
                             (((col >> 3) ^ (row & 7)) << 4) + (col & 7) * 2) = u;
            }
        asm volatile("s_waitcnt vmcnt(0) lgkmcnt(0)" ::: "memory");
    }
    __builtin_amdgcn_s_barrier();

    auto G1 = [&](int st, f32x4* a1) {
        const u16* xc = &xs[(st >> 1) & 1][0];
        int rbase = (st & 1) * 32 + wr * 16 + l15;
#pragma unroll
        for (int nt = 0; nt < 4; nt++) a1[nt] = (f32x4){0.f, 0.f, 0.f, 0.f};
#pragma unroll
        for (int kb = 0; kb < 4; kb++) {
            int kg = kb * 4 + l4;
            short8 a = *(const short8*)&xc[rbase * 128 + ((kg ^ (rbase & 7)) << 3)];
#pragma unroll
            for (int nt = 0; nt < 4; nt++) {
                int fr = wq * 64 + nt * 16 + l15;
                short8 bb = *(const short8*)&w1s[fr * 128 + ((kg ^ (fr & 7)) << 3)];
                a1[nt] = __builtin_amdgcn_mfma_f32_16x16x32_bf16(a, bb, a1[nt], 0, 0, 0);
            }
        }
    };
    auto GELU_ST = [&](int st, f32x4* a1) {
        u16* hd = &hb[st & 1][0];
#pragma unroll
        for (int nt = 0; nt < 4; nt++) {
            int fcol = wq * 64 + nt * 16 + l15;
#pragma unroll
            for (int j = 0; j < 4; j++) {
                int row = wr * 16 + l4 * 4 + j;
                float v = a1[nt][j] + b1v[nt];
                v = gelu_fast(v) * gw;
                hd[row * 256 + ((((fcol >> 3) ^ (row & 7)) << 3) | (fcol & 7))] = f2bf(v);
            }
        }
    };
    auto G2 = [&](int st, f32x4* a2) {
        const u16* hs = &hb[st & 1][0];
        int arow = wr * 16 + l15;
        a2[0] = (f32x4){0.f, 0.f, 0.f, 0.f};
        a2[1] = (f32x4){0.f, 0.f, 0.f, 0.f};
#pragma unroll
        for (int kb = 0; kb < 8; kb++) {
            int fg = kb * 4 + l4;
            short8 a = *(const short8*)&hs[arow * 256 + ((fg ^ (arow & 7)) << 3)];
            a2[0] = __builtin_amdgcn_mfma_f32_16x16x32_bf16(a, w2f[0][kb], a2[0], 0, 0, 0);
            a2[1] = __builtin_amdgcn_mfma_f32_16x16x32_bf16(a, w2f[1][kb], a2[1], 0, 0, 0);
        }
    };
    auto OWRITE = [&](int st, f32x4* a2) {
        u16* od = &ob[st & 1][0];
        const u16* xc = &xs[(st >> 1) & 1][0];
#pragma unroll
        for (int n = 0; n < 2; n++) {
            int d = wq * 32 + n * 16 + l15;
#pragma unroll
            for (int j = 0; j < 4; j++) {
                int row = wr * 16 + l4 * 4 + j;
                int xrow = (st & 1) * 32 + row;
                float xr = bf2f(xc[xrow * 128 + ((((d >> 3) ^ (xrow & 7)) << 3) | (d & 7))]);
                od[row * 128 + (d ^ ((row & 7) << 3))] = f2bf(a2[n][j] + bcv[n] + xr);
            }
        }
    };
    auto YSTV = [&](int st) {
        int row = t >> 4;
        int cg = t & 15;
        const u16* os = &ob[st & 1][0];
        short8 v = *(const short8*)&os[row * 128 + ((cg ^ (row & 7)) << 3)];
        u16* yb = y + xbase + (size_t)grp * 65536 + st * 4096;
        *(short8*)&yb[row * 128 + cg * 8] = v;
    };

    {
        f32x4 a1[4];
        G1(0, a1);
        GELU_ST(0, a1);
    }
    asm volatile("s_waitcnt lgkmcnt(0)" ::: "memory");
    __builtin_amdgcn_s_barrier();

    for (int st = 0; st < 17; ++st) {
        const bool stg = (st < 16) && ((st & 1) == 0) && st >= 2 && st <= 12;
        if (st < 16) {
            f32x4 a1n[4];
            if (st < 15) G1(st + 1, a1n);
            f32x4 a2[2];
            G2(st, a2);
            if (st < 15) GELU_ST(st + 1, a1n);
            OWRITE(st, a2);
        }
        if (stg) {
            int T = st / 2 + 1;
            if (XB) {
                const u16* xbp = (const u16*)xsrc_;
                gload_lds16(xbp + gbase + T * 8192 + t * 8, (char*)&xs[T & 1][0] + t * 16);
                gload_lds16(xbp + gbase + T * 8192 + 4096 + t * 8,
                            (char*)&xs[T & 1][0] + 8192 + t * 16);
            } else {
                const float* xf = (const float*)xsrc_;
#pragma unroll
                for (int p = 0; p < 4; p++) {
                    int elem = p * 2048 + t * 4;
                    int row = elem >> 7, col = elem & 127;
                    float4 v = *(const float4*)&xf[gbase + T * 8192 + elem];
                    ushort4v u;
                    u.x = f2bf(v.x); u.y = f2bf(v.y); u.z = f2bf(v.z); u.w = f2bf(v.w);
                    *(ushort4v*)((char*)&xs[T & 1][0] + row * 256 +
                                 (((col >> 3) ^ (row & 7)) << 4) + (col & 7) * 2) = u;
                }
            }
        }
        if (st >= 1) YSTV(st - 1);
        asm volatile("s_waitcnt lgkmcnt(0)" ::: "memory");
        if (stg && XB) asm volatile("s_waitcnt vmcnt(1)" ::: "memory");
        if (st < 16) __builtin_amdgcn_s_barrier();
    }
}

// ---------------- Kernel 5: out = y @ w3^T + b3, 256^2 pipelined -----------
// R6 schedule (best measured). NEW XCD swizzle: XCD k owns an 8-row mblk
// strip x all 8 nblk; concurrent blocks on an XCD share A-panels (4x reuse)
// and B-panels (8x reuse) through their K-phase slice (~384KB) -> L2-fill
// traffic ~halves vs column-panel-per-XCD mapping.
#define BARX() do { asm volatile("" ::: "memory"); __builtin_amdgcn_s_barrier(); \
                    asm volatile("" ::: "memory"); } while (0)

#define WLG(NSTR) do { asm volatile("s_waitcnt lgkmcnt(" NSTR ")" ::: "memory"); \
                       __builtin_amdgcn_sched_barrier(0); } while (0)

#define DSA(mh, c) do { \
    const char* _ba = smem + (c) * 65536 + abase; \
    _Pragma("unroll") for (int mf = 0; mf < 4; mf++) \
    _Pragma("unroll") for (int kk = 0; kk < 2; kk++) \
        areg[mf][kk] = *(const short8*)(_ba + ((mh) * 4 + mf) * 2048 + kof[kk]); \
} while (0)

#define DSB(nh, c) do { \
    const char* _bb = smem + (c) * 65536 + bbase; \
    _Pragma("unroll") for (int nf = 0; nf < 2; nf++) \
    _Pragma("unroll") for (int kk = 0; kk < 2; kk++) \
        breg[(nh) * 2 + nf][kk] = *(const short8*)(_bb + ((nh) * 2 + nf) * 2048 + kof[kk]); \
} while (0)

#define MMAQ(mh, nh) do { \
    __builtin_amdgcn_s_setprio(1); \
    _Pragma("unroll") for (int mf = 0; mf < 4; mf++) \
    _Pragma("unroll") for (int nf = 0; nf < 2; nf++) \
    _Pragma("unroll") for (int kk = 0; kk < 2; kk++) \
        acc[(mh) * 4 + mf][(nh) * 2 + nf] = __builtin_amdgcn_mfma_f32_16x16x32_bf16( \
            areg[mf][kk], breg[(nh) * 2 + nf][kk], acc[(mh) * 4 + mf][(nh) * 2 + nf], 0, 0, 0); \
    __builtin_amdgcn_s_setprio(0); \
} while (0)

#define STG(op, c, h, kt) do { \
    const u16* _gs = (op) ? wbp : yap; \
    int _tr0 = (op) ? nrow0 : mrow0; \
    _Pragma("unroll") for (int p = 0; p < 2; p++) { \
        int _idx = p * 512 + t; \
        int _row = _idx >> 3; \
        int _gcol = (((_idx & 7) ^ (_row & 7)) << 3); \
        gload_lds16(_gs + (size_t)(_tr0 + (h) * 128 + _row) * 2048 + (kt) * 64 + _gcol, \
                    smem + (c) * 65536 + (op) * 32768 + (h) * 16384 + _idx * 16); \
    } \
} while (0)

__global__ __launch_bounds__(512, 2) void final_gemm256(const u16* __restrict__ yap,
                                                        const u16* __restrict__ wbp,
                                                        const float* __restrict__ b3,
                                                        float* __restrict__ out) {
    extern __shared__ char smem[];
    const int t = threadIdx.x;
    const int lane = t & 63, w = t >> 6;
    const int wm = w >> 2, wn = w & 3;
    const int l15 = lane & 15, l4 = lane >> 4, sx = lane & 7;

    // Row-strip XCD swizzle: XCD (bid&7) owns mblk in [8k, 8k+8), nblk fast.
    int bid = blockIdx.x;
    int xcd = bid & 7, q = bid >> 3;
    const int mrow0 = (xcd * 8 + (q >> 3)) * 256;
    const int nrow0 = (q & 7) * 256;

    const int abase = wm * 16384 + l15 * 128;
    const int bbase = 32768 + (wn >> 1) * 16384 + ((wn & 1) * 64 + l15) * 128;
    int kof[2];
#pragma unroll
    for (int kk = 0; kk < 2; kk++) kof[kk] = ((kk * 4 + l4) ^ sx) << 4;

    f32x4 acc[8][4];
#pragma unroll
    for (int m = 0; m < 8; m++)
#pragma unroll
        for (int n = 0; n < 4; n++) acc[m][n] = (f32x4){0.f, 0.f, 0.f, 0.f};
    short8 areg[4][2];
    short8 breg[4][2];

    STG(0, 0, 0, 0); STG(0, 0, 1, 0); STG(1, 0, 0, 0); STG(1, 0, 1, 0);
    STG(0, 1, 0, 1); STG(0, 1, 1, 1); STG(1, 1, 0, 1); STG(1, 1, 1, 1);
    asm volatile("s_waitcnt vmcnt(8)" ::: "memory");
    BARX();
    DSA(0, 0); DSB(0, 0); DSB(1, 0);

    for (int it2 = 0; it2 < 16; ++it2) {
#pragma unroll
        for (int c = 0; c < 2; ++c) {
            const int tt = 2 * it2 + c;
            WLG("4");  MMAQ(0, 0);
            WLG("0");  MMAQ(0, 1);
            DSA(1, c);
            WLG("0");  MMAQ(1, 0);
            asm volatile("s_waitcnt vmcnt(0)" ::: "memory");
            BARX();
            if (tt < 30) { STG(0, c, 0, tt + 2); STG(0, c, 1, tt + 2);
                           STG(1, c, 0, tt + 2); STG(1, c, 1, tt + 2); }
            MMAQ(1, 1);
            if (tt < 31) { DSA(0, c ^ 1); DSB(0, c ^ 1); DSB(1, c ^ 1); }
        }
    }

#pragma unroll
    for (int m = 0; m < 8; m++)
#pragma unroll
        for (int n = 0; n < 4; n++) {
            int col = nrow0 + wn * 64 + n * 16 + l15;
            float bias = b3[col];
            int row = mrow0 + wm * 128 + m * 16 + l4 * 4;
#pragma unroll
            for (int j = 0; j < 4; j++)
                out[(size_t)(row + j) * 2048 + col] = acc[m][n][j] + bias;
        }
}

// ---------------------------------------------------------------------------
extern "C" void kernel_launch(void* const* d_in, const int* in_sizes, int n_in,
                              void* d_out, int out_size, void* d_ws, size_t ws_size,
                              hipStream_t stream) {
    const float* x   = (const float*)d_in[0];
    const float* sw  = (const float*)d_in[1];
    const float* swb = (const float*)d_in[2];
    const float* w1  = (const float*)d_in[3];
    const float* b1  = (const float*)d_in[4];
    const float* w2  = (const float*)d_in[5];
    const float* b2  = (const float*)d_in[6];
    const float* w3  = (const float*)d_in[7];
    const float* b3  = (const float*)d_in[8];
    float* out = (float*)d_out;

    char* ws = (char*)d_ws;
    float* part = (float*)(ws + 0);                 // 128 KB
    float* gate = (float*)(ws + 131072);            // 64 B
    int*   idx  = (int*)(ws + 131136);              // 64 B
    float* bc   = (float*)(ws + 131200);            // 4 KB
    u16*   w1b  = (u16*)(ws + 262144);              // 256 KB (swizzled)
    u16*   w2b  = (u16*)(ws + 524288);              // 256 KB
    u16*   w3b  = (u16*)(ws + 786432);              // 8 MB
    u16*   y    = (u16*)(ws + 9175040);             // 64 MB
    u16*   xb   = (u16*)(ws + 76283904);            // 64 MB (swizzled bf16 x)
    const size_t need_xb = 143392768;
    const bool xbmode = ws_size >= need_xb;

    hipFuncSetAttribute((const void*)final_gemm256,
                        hipFuncAttributeMaxDynamicSharedMemorySize, 131072);

    if (xbmode)
        hipLaunchKernelGGL((router_partial<1>), dim3(NCHUNK), dim3(256), 0, stream, x, sw, part, xb);
    else
        hipLaunchKernelGGL((router_partial<0>), dim3(NCHUNK), dim3(256), 0, stream, x, sw, part, xb);
    hipLaunchKernelGGL(router_finish, dim3(1), dim3(512), 0, stream, part, swb, b2, gate, idx, bc);
    hipLaunchKernelGGL(convert_w12, dim3(256), dim3(256), 0, stream, w1, w2, w1b, w2b);
    hipLaunchKernelGGL(convert_w3, dim3(D_ * D_ / 1024), dim3(256), 0, stream, w3, w3b);
    if (xbmode)
        hipLaunchKernelGGL((mlp_kernel<1>), dim3(64, 8), dim3(512), 0, stream,
                           (const void*)xb, w1b, w2b, b1, gate, idx, bc, y);
    else
        hipLaunchKernelGGL((mlp_kernel<0>), dim3(64, 8), dim3(512), 0, stream,
                           (const void*)x, w1b, w2b, b1, gate, idx, bc, y);
    hipLaunchKernelGGL(final_gemm256, dim3(512), dim3(512), 131072, stream,
                       y, w3b, b3, out);
}